// Round 1
// baseline (11253.875 us; speedup 1.0000x reference)
//
#include <hip/hip_runtime.h>
#include <hip/hip_bf16.h>

// Sizes
#define Dm   1024
#define Hn   16
#define KVH  4
#define DH   64
#define CHUNK 256
#define SDIM 128
#define MG   8
#define Bn   4
#define Tn   4096
#define TC   264            // MG + CHUNK
#define NSTEP 16
#define TD   4194304L       // Tn*Dm per batch

// ---------------- utility kernels ----------------

__global__ __launch_bounds__(512) void vcopy_k(const float* __restrict__ s, float* __restrict__ d, int n) {
    int i = blockIdx.x * 512 + threadIdx.x;
    if (i < n) d[i] = s[i];
}

__global__ __launch_bounds__(256) void fill_globals_k(const float* __restrict__ gtok, float* __restrict__ h_in) {
    int idx = blockIdx.x * 256 + threadIdx.x;      // 0..32767  (4 b * 8 rows * 1024)
    int b = idx >> 13, rd = idx & 8191;
    h_in[(long)b * (TC * Dm) + rd] = gtok[rd];
}

// si[b][d] = sum_s st[b][s] * Wsi[d][s] + bsi[d]
__global__ __launch_bounds__(256) void state_proj_k(const float* __restrict__ st, const float* __restrict__ Wsi,
                                                    const float* __restrict__ bsi, float* __restrict__ si) {
    int idx = blockIdx.x * 256 + threadIdx.x;      // 0..4095
    int b = idx >> 10, d = idx & 1023;
    const float* sr = st + b * SDIM;
    const float* wr = Wsi + (long)d * SDIM;
    float a = bsi[d];
#pragma unroll 4
    for (int k = 0; k < SDIM; ++k) a += sr[k] * wr[k];
    si[idx] = a;
}

// LayerNorm of one 1024-row per block; optional per-batch add vector (si)
__global__ __launch_bounds__(256) void ln_rows_k(const float* __restrict__ in, long inS, long inRoff,
                                                 float* __restrict__ out, long outS, long outRoff,
                                                 const float* __restrict__ g, const float* __restrict__ be,
                                                 const float* __restrict__ add) {
    int r = blockIdx.x, b = blockIdx.y, tid = threadIdx.x;
    const float* row = in + (long)b * inS + (inRoff + r) * (long)Dm;
    float4 v = *(const float4*)(row + tid * 4);
    float s = v.x + v.y + v.z + v.w;
    float q = v.x * v.x + v.y * v.y + v.z * v.z + v.w * v.w;
    for (int off = 32; off > 0; off >>= 1) { s += __shfl_down(s, off); q += __shfl_down(q, off); }
    __shared__ float red[10];
    int w = tid >> 6;
    if ((tid & 63) == 0) { red[w] = s; red[4 + w] = q; }
    __syncthreads();
    if (tid == 0) {
        float ts = red[0] + red[1] + red[2] + red[3];
        float tq = red[4] + red[5] + red[6] + red[7];
        float mean = ts * (1.f / Dm);
        float var = tq * (1.f / Dm) - mean * mean;
        red[8] = mean;
        red[9] = rsqrtf(var + 1e-5f);
    }
    __syncthreads();
    float mean = red[8], rstd = red[9];
    int d = tid * 4;
    float4 gv = *(const float4*)(g + d);
    float4 bv = *(const float4*)(be + d);
    float4 o;
    o.x = (v.x - mean) * rstd * gv.x + bv.x;
    o.y = (v.y - mean) * rstd * gv.y + bv.y;
    o.z = (v.z - mean) * rstd * gv.z + bv.z;
    o.w = (v.w - mean) * rstd * gv.w + bv.w;
    if (add) {
        float4 av = *(const float4*)(add + b * Dm + d);
        o.x += av.x; o.y += av.y; o.z += av.z; o.w += av.w;
    }
    *(float4*)(out + (long)b * outS + (outRoff + r) * (long)Dm + d) = o;
}

// ---------------- generic f32 GEMM:  C = act(A @ W^T + bias + residual) ----------------
// A rows indexed m: row ptr = A + (m/AR)*AS + (m%AR + ARoff)*K
// W rows piecewise over n: n<nb1 -> Wa+n*K ; n<nb2 -> Wb+(n-nb1)*K ; else Wc+(n-nb2)*K
__global__ __launch_bounds__(256) void gemm_f32(
    const float* __restrict__ A, long AS, int AR, long ARoff,
    const float* __restrict__ Wa, const float* __restrict__ Wb, const float* __restrict__ Wc,
    int nb1, int nb2,
    float* __restrict__ C, long CS, int CR, long CRoff, int ldc,
    const float* __restrict__ bias,
    const float* __restrict__ Rz, long RS, int RR, long RRoff, int ldr,
    int act, int M, int N, int K)
{
    __shared__ float As[16][68];
    __shared__ float Ws[16][68];
    int tid = threadIdx.x;
    int tx = tid & 15, ty = tid >> 4;
    int m0 = blockIdx.y << 6, n0 = blockIdx.x << 6;
    int lr = tid >> 2, lc = (tid & 3) << 2;

    int am = m0 + lr;
    const float* Arow = nullptr;
    if (am < M) Arow = A + (long)(am / AR) * AS + (long)(am % AR + ARoff) * K;
    int wn = n0 + lr;
    const float* Wrow;
    if (wn < nb1) Wrow = Wa + (long)wn * K;
    else if (wn < nb2) Wrow = Wb + (long)(wn - nb1) * K;
    else Wrow = Wc + (long)(wn - nb2) * K;

    float acc[4][4];
#pragma unroll
    for (int i = 0; i < 4; ++i)
#pragma unroll
        for (int j = 0; j < 4; ++j) acc[i][j] = 0.f;

    for (int k0 = 0; k0 < K; k0 += 16) {
        float4 av = make_float4(0.f, 0.f, 0.f, 0.f);
        if (Arow) av = *(const float4*)(Arow + k0 + lc);
        float4 wv = *(const float4*)(Wrow + k0 + lc);
        __syncthreads();
        As[lc + 0][lr] = av.x; As[lc + 1][lr] = av.y; As[lc + 2][lr] = av.z; As[lc + 3][lr] = av.w;
        Ws[lc + 0][lr] = wv.x; Ws[lc + 1][lr] = wv.y; Ws[lc + 2][lr] = wv.z; Ws[lc + 3][lr] = wv.w;
        __syncthreads();
#pragma unroll
        for (int kk = 0; kk < 16; ++kk) {
            float4 a4 = *(const float4*)&As[kk][ty << 2];
            float4 b4 = *(const float4*)&Ws[kk][tx << 2];
            float aa[4] = { a4.x, a4.y, a4.z, a4.w };
            float bb[4] = { b4.x, b4.y, b4.z, b4.w };
#pragma unroll
            for (int i = 0; i < 4; ++i)
#pragma unroll
                for (int j = 0; j < 4; ++j) acc[i][j] += aa[i] * bb[j];
        }
    }

#pragma unroll
    for (int i = 0; i < 4; ++i) {
        int m = m0 + (ty << 2) + i;
        if (m >= M) continue;
        float* crow = C + (long)(m / CR) * CS + (long)(m % CR + CRoff) * ldc;
        const float* rrow = nullptr;
        if (Rz) rrow = Rz + (long)(m / RR) * RS + (long)(m % RR + RRoff) * ldr;
#pragma unroll
        for (int j = 0; j < 4; ++j) {
            int n = n0 + (tx << 2) + j;
            float v = acc[i][j];
            if (bias) v += bias[n];
            if (rrow) v += rrow[n];
            if (act == 1) v = 0.5f * v * (1.f + erff(v * 0.70710678118654752f));
            crow[n] = v;
        }
    }
}

// ---------------- attention ----------------
// grid (qc=4, head=16, b=4), 64 threads (1 wave). Lane owns query qi = 8 + qc*64 + lane.
// K/V for kv-head staged in LDS per 64-key tile; online softmax in registers.
__global__ __launch_bounds__(64) void attn_k(const float* __restrict__ qkv, float* __restrict__ o_mat) {
    int qc = blockIdx.x, head = blockIdx.y, b = blockIdx.z;
    int kvh = head >> 2;
    int lane = threadIdx.x;
    int qi = MG + qc * 64 + lane;
    const float scale = 0.125f;

    float q[64];
    const float* qrow = qkv + ((long)(b * TC + qi) * 1536 + head * DH);
#pragma unroll
    for (int d4 = 0; d4 < 16; ++d4) {
        float4 t = *(const float4*)(qrow + d4 * 4);
        q[d4 * 4 + 0] = t.x * scale; q[d4 * 4 + 1] = t.y * scale;
        q[d4 * 4 + 2] = t.z * scale; q[d4 * 4 + 3] = t.w * scale;
    }
    float o[64];
#pragma unroll
    for (int d = 0; d < 64; ++d) o[d] = 0.f;
    float mmax = -1e30f, l = 0.f;

    int jmax = MG + qc * 64 + 63;   // inclusive max key in this block
    __shared__ float ks[64][64];
    __shared__ float vs[64][64];
    int lrow = lane >> 4;
    int lcol = (lane & 15) << 2;

    for (int jt = 0; jt <= jmax; jt += 64) {
        int ntk = min(64, jmax + 1 - jt);
        for (int rr = 0; rr < 64; rr += 4) {
            int r = rr + lrow;
            if (r < ntk) {
                const float* krow = qkv + ((long)(b * TC + jt + r) * 1536 + 1024 + kvh * DH);
                *(float4*)&ks[r][lcol] = *(const float4*)(krow + lcol);
                *(float4*)&vs[r][lcol] = *(const float4*)(krow + 256 + lcol);
            }
        }
        __syncthreads();
        for (int j = 0; j < ntk; ++j) {
            float s = -1e30f;
            if (jt + j <= qi) {
                float dot = 0.f;
#pragma unroll
                for (int d4 = 0; d4 < 16; ++d4) {
                    float4 k4 = *(const float4*)&ks[j][d4 * 4];
                    dot += q[d4 * 4 + 0] * k4.x + q[d4 * 4 + 1] * k4.y
                         + q[d4 * 4 + 2] * k4.z + q[d4 * 4 + 3] * k4.w;
                }
                s = dot;
            }
            float mnew = fmaxf(mmax, s);
            float r = __expf(mmax - mnew);
            float p = __expf(s - mnew);
            l = l * r + p;
#pragma unroll
            for (int d4 = 0; d4 < 16; ++d4) {
                float4 v4 = *(const float4*)&vs[j][d4 * 4];
                o[d4 * 4 + 0] = o[d4 * 4 + 0] * r + p * v4.x;
                o[d4 * 4 + 1] = o[d4 * 4 + 1] * r + p * v4.y;
                o[d4 * 4 + 2] = o[d4 * 4 + 2] * r + p * v4.z;
                o[d4 * 4 + 3] = o[d4 * 4 + 3] * r + p * v4.w;
            }
            mmax = mnew;
        }
        __syncthreads();
    }
    float inv = 1.f / l;
    float* orow = o_mat + ((long)(b * CHUNK + qc * 64 + lane) * Dm + head * DH);
#pragma unroll
    for (int d4 = 0; d4 < 16; ++d4) {
        float4 t = make_float4(o[d4 * 4 + 0] * inv, o[d4 * 4 + 1] * inv,
                               o[d4 * 4 + 2] * inv, o[d4 * 4 + 3] * inv);
        *(float4*)(orow + d4 * 4) = t;
    }
}

// mean over 256 chunk rows -> mean_c[b][d]
__global__ __launch_bounds__(256) void col_mean_k(const float* __restrict__ c, long stepOff, float* __restrict__ mean_c) {
    int b = blockIdx.y;
    int d = blockIdx.x * 256 + threadIdx.x;
    const float* base = c + (long)b * TD + stepOff + d;
    float s = 0.f;
    for (int r = 0; r < CHUNK; ++r) s += base[(long)r * Dm];
    mean_c[b * Dm + d] = s * (1.f / CHUNK);
}

// st[b][ss] = mean_c[b] . Wsp[ss] + bsp[ss]
__global__ __launch_bounds__(128) void state_update_k(const float* __restrict__ mean_c, const float* __restrict__ Wsp,
                                                      const float* __restrict__ bsp, float* __restrict__ st) {
    int b = blockIdx.x, ss = threadIdx.x;
    const float* mr = mean_c + b * Dm;
    const float* wr = Wsp + (long)ss * Dm;
    float a = bsp[ss];
#pragma unroll 4
    for (int d = 0; d < Dm; ++d) a += mr[d] * wr[d];
    st[b * SDIM + ss] = a;
}

// ---------------- orchestration ----------------

extern "C" void kernel_launch(void* const* d_in, const int* in_sizes, int n_in,
                              void* d_out, int out_size, void* d_ws, size_t ws_size,
                              hipStream_t stream) {
    const float* x     = (const float*)d_in[0];
    const float* state = (const float*)d_in[1];
    const float* Wq    = (const float*)d_in[2];
    const float* Wk    = (const float*)d_in[3];
    const float* Wv    = (const float*)d_in[4];
    const float* Wo    = (const float*)d_in[5];
    const float* bo    = (const float*)d_in[6];
    const float* lag   = (const float*)d_in[7];
    const float* lab   = (const float*)d_in[8];
    const float* lfg   = (const float*)d_in[9];
    const float* lfb   = (const float*)d_in[10];
    const float* W1    = (const float*)d_in[11];
    const float* b1    = (const float*)d_in[12];
    const float* W2    = (const float*)d_in[13];
    const float* b2    = (const float*)d_in[14];
    const float* Wsp   = (const float*)d_in[15];
    const float* bsp   = (const float*)d_in[16];
    const float* Wsi   = (const float*)d_in[17];
    const float* bsi   = (const float*)d_in[18];
    const float* gtok  = (const float*)d_in[19];

    float* out = (float*)d_out;
    float* ws  = (float*)d_ws;

    // workspace layout (floats)
    float* h_in   = ws;                      // 4*264*1024   = 1081344
    float* qkv    = h_in + 1081344;          // 4*264*1536   = 1622016
    float* o_mat  = qkv + 1622016;           // 4*256*1024   = 1048576
    float* si     = o_mat + 1048576;         // 4096
    float* t_ln   = si + 4096;               // 1048576
    float* u      = t_ln + 1048576;          // 4*256*4096   = 4194304
    float* mean_c = u + 4194304;             // 4096
    float* st     = mean_c + 4096;           // 512

    vcopy_k<<<1, 512, 0, stream>>>(state, st, 512);
    fill_globals_k<<<128, 256, 0, stream>>>(gtok, h_in);

    const int BIG = 1 << 30;
    for (int s = 0; s < NSTEP; ++s) {
        long roff = (long)s * CHUNK;           // row offset within a batch of out/x
        state_proj_k<<<16, 256, 0, stream>>>(st, Wsi, bsi, si);
        // attn LN -> h_in rows 8..263
        ln_rows_k<<<dim3(256, 4), 256, 0, stream>>>(x, TD, roff, h_in, (long)TC * Dm, MG, lag, lab, si);
        // QKV: [1056 x 1536 x 1024]
        gemm_f32<<<dim3(24, 17), 256, 0, stream>>>(
            h_in, (long)TC * Dm, TC, 0L,
            Wq, Wk, Wv, 1024, 1280,
            qkv, (long)TC * 1536, TC, 0L, 1536,
            nullptr,
            nullptr, 0L, 1, 0L, 0,
            0, Bn * TC, 1536, 1024);
        attn_k<<<dim3(4, 16, 4), 64, 0, stream>>>(qkv, o_mat);
        // Wo + bo + residual(x chunk) -> out chunk (c_pre)
        gemm_f32<<<dim3(16, 16), 256, 0, stream>>>(
            o_mat, (long)CHUNK * Dm, CHUNK, 0L,
            Wo, Wo, Wo, BIG, BIG,
            out, TD, CHUNK, roff, Dm,
            bo,
            x, TD, CHUNK, roff, Dm,
            0, Bn * CHUNK, 1024, 1024);
        // ffn LN
        ln_rows_k<<<dim3(256, 4), 256, 0, stream>>>(out, TD, roff, t_ln, (long)CHUNK * Dm, 0, lfg, lfb, nullptr);
        // FFN1 + gelu
        gemm_f32<<<dim3(64, 16), 256, 0, stream>>>(
            t_ln, (long)CHUNK * Dm, CHUNK, 0L,
            W1, W1, W1, BIG, BIG,
            u, (long)CHUNK * 4096, CHUNK, 0L, 4096,
            b1,
            nullptr, 0L, 1, 0L, 0,
            1, Bn * CHUNK, 4096, 1024);
        // FFN2 + b2 + residual(c_pre) -> out chunk (final c)
        gemm_f32<<<dim3(16, 16), 256, 0, stream>>>(
            u, (long)CHUNK * 4096, CHUNK, 0L,
            W2, W2, W2, BIG, BIG,
            out, TD, CHUNK, roff, Dm,
            b2,
            out, TD, CHUNK, roff, Dm,
            0, Bn * CHUNK, 1024, 4096);
        // state update
        col_mean_k<<<dim3(4, 4), 256, 0, stream>>>(out, roff * Dm, mean_c);
        state_update_k<<<4, 128, 0, stream>>>(mean_c, Wsp, bsp, st);
    }
    vcopy_k<<<1, 512, 0, stream>>>(st, out + (long)Bn * Tn * Dm, 512);
}

// Round 2
// 6669.556 us; speedup vs baseline: 1.6874x; 1.6874x over previous
//
#include <hip/hip_runtime.h>
#include <hip/hip_bf16.h>

// Sizes
#define Dm    1024
#define Hn    16
#define KVH   4
#define DH    64
#define CHUNK 256
#define SDIM  128
#define MG    8
#define Bn    4
#define Tn    4096
#define TC    264            // MG + CHUNK
#define NSTEP 16
#define TD    4194304L       // Tn*Dm per batch

typedef __attribute__((ext_vector_type(8))) short short8;
typedef __attribute__((ext_vector_type(4))) float floatx4;
typedef __hip_bfloat16 bf16;

__device__ __forceinline__ void gl16(const void* g, void* l) {
    using GP = const __attribute__((address_space(1))) char*;
    using LP = __attribute__((address_space(3))) char*;
    __builtin_amdgcn_global_load_lds((GP)g, (LP)l, 16, 0, 0);
}

// ---------------- utility kernels ----------------

__global__ __launch_bounds__(512) void vcopy_k(const float* __restrict__ s, float* __restrict__ d, int n) {
    int i = blockIdx.x * 512 + threadIdx.x;
    if (i < n) d[i] = s[i];
}

__global__ __launch_bounds__(256) void cvt_bf16_k(const float* __restrict__ s, bf16* __restrict__ d, int n4) {
    int i = blockIdx.x * 256 + threadIdx.x;
    if (i >= n4) return;
    float4 v = ((const float4*)s)[i];
    bf16* o = d + i * 4;
    o[0] = __float2bfloat16(v.x); o[1] = __float2bfloat16(v.y);
    o[2] = __float2bfloat16(v.z); o[3] = __float2bfloat16(v.w);
}

__global__ __launch_bounds__(256) void fill_globals_k(const float* __restrict__ gtok, bf16* __restrict__ h_in) {
    int idx = blockIdx.x * 256 + threadIdx.x;      // 0..32767  (4 b * 8 rows * 1024)
    int b = idx >> 13, rd = idx & 8191;
    h_in[(long)b * (TC * Dm) + rd] = __float2bfloat16(gtok[rd]);
}

// si[b][d] = sum_s st[b][s] * Wsi[d][s] + bsi[d]
__global__ __launch_bounds__(256) void state_proj_k(const float* __restrict__ st, const float* __restrict__ Wsi,
                                                    const float* __restrict__ bsi, float* __restrict__ si) {
    int idx = blockIdx.x * 256 + threadIdx.x;      // 0..4095
    int b = idx >> 10, d = idx & 1023;
    const float* sr = st + b * SDIM;
    const float* wr = Wsi + (long)d * SDIM;
    float a = bsi[d];
#pragma unroll 4
    for (int k = 0; k < SDIM; ++k) a += sr[k] * wr[k];
    si[idx] = a;
}

// LayerNorm of one 1024-row per block; optional per-batch add vector (si). bf16 output.
__global__ __launch_bounds__(256) void ln_rows_k(const float* __restrict__ in, long inS, long inRoff,
                                                 bf16* __restrict__ out, long outS, long outRoff,
                                                 const float* __restrict__ g, const float* __restrict__ be,
                                                 const float* __restrict__ add) {
    int r = blockIdx.x, b = blockIdx.y, tid = threadIdx.x;
    const float* row = in + (long)b * inS + (inRoff + r) * (long)Dm;
    float4 v = *(const float4*)(row + tid * 4);
    float s = v.x + v.y + v.z + v.w;
    float q = v.x * v.x + v.y * v.y + v.z * v.z + v.w * v.w;
    for (int off = 32; off > 0; off >>= 1) { s += __shfl_down(s, off); q += __shfl_down(q, off); }
    __shared__ float red[10];
    int w = tid >> 6;
    if ((tid & 63) == 0) { red[w] = s; red[4 + w] = q; }
    __syncthreads();
    if (tid == 0) {
        float ts = red[0] + red[1] + red[2] + red[3];
        float tq = red[4] + red[5] + red[6] + red[7];
        float mean = ts * (1.f / Dm);
        float var = tq * (1.f / Dm) - mean * mean;
        red[8] = mean;
        red[9] = rsqrtf(var + 1e-5f);
    }
    __syncthreads();
    float mean = red[8], rstd = red[9];
    int d = tid * 4;
    float4 gv = *(const float4*)(g + d);
    float4 bv = *(const float4*)(be + d);
    float o0 = (v.x - mean) * rstd * gv.x + bv.x;
    float o1 = (v.y - mean) * rstd * gv.y + bv.y;
    float o2 = (v.z - mean) * rstd * gv.z + bv.z;
    float o3 = (v.w - mean) * rstd * gv.w + bv.w;
    if (add) {
        float4 av = *(const float4*)(add + b * Dm + d);
        o0 += av.x; o1 += av.y; o2 += av.z; o3 += av.w;
    }
    bf16* orow = out + (long)b * outS + (outRoff + r) * (long)Dm + d;
    orow[0] = __float2bfloat16(o0); orow[1] = __float2bfloat16(o1);
    orow[2] = __float2bfloat16(o2); orow[3] = __float2bfloat16(o3);
}

// ---------------- bf16 MFMA GEMM:  C = act(A @ W^T + bias + residual) ----------------
// A: [Mpad][K] bf16 row-major (M = real rows for store guard). W: [N][K] bf16 row-major.
// flags: 0 = f32 out (row-mapped via CR/CS/CRoff/ldc) + optional bias + optional residual Rz (same mapping)
//        1 = bf16 out contiguous ldc + bias + exact GELU
__global__ __launch_bounds__(256) void gemm_bf16(
    const bf16* __restrict__ A, const bf16* __restrict__ W,
    int M, int N, int K,
    float* __restrict__ Cf, const float* __restrict__ Rz,
    bf16* __restrict__ Cb, const float* __restrict__ bias,
    int CR, long CS, long CRoff, int ldc, int flags)
{
    __shared__ short As[128 * 32];
    __shared__ short Bs[128 * 32];
    int tid = threadIdx.x;
    int w = tid >> 6, l = tid & 63;
    int wr = w >> 1, wc = w & 1;
    int m0 = blockIdx.y << 7, n0 = blockIdx.x << 7;

    // staging: tile 128x32 bf16 = 8KB = 8 segs of 1KB; wave w owns segs {w, w+4}
    int r0 = w * 16 + (l >> 2);          // row for seg w
    int kc = (l & 3) << 3;               // k elem offset (8 bf16 = 16B)
    const bf16* pA0 = A + (long)(m0 + r0) * K + kc;
    const bf16* pA1 = pA0 + (long)64 * K;
    const bf16* pW0 = W + (long)(n0 + r0) * K + kc;
    const bf16* pW1 = pW0 + (long)64 * K;
    char* lA0 = (char*)As + w * 1024 + l * 16;
    char* lA1 = (char*)As + 4096 + w * 1024 + l * 16;
    char* lB0 = (char*)Bs + w * 1024 + l * 16;
    char* lB1 = (char*)Bs + 4096 + w * 1024 + l * 16;

    floatx4 acc[4][4];
#pragma unroll
    for (int i = 0; i < 4; ++i)
#pragma unroll
        for (int j = 0; j < 4; ++j) acc[i][j] = (floatx4){0.f, 0.f, 0.f, 0.f};

    int arow = wr * 64 + (l & 15);
    int brow = wc * 64 + (l & 15);
    int acol = (l >> 4) << 3;

    for (int kt = 0; kt < K; kt += 32) {
        gl16(pA0 + kt, lA0);
        gl16(pA1 + kt, lA1);
        gl16(pW0 + kt, lB0);
        gl16(pW1 + kt, lB1);
        __syncthreads();                 // drains vmcnt(0): LDS tile ready
        short8 a[4], b[4];
#pragma unroll
        for (int t = 0; t < 4; ++t) {
            a[t] = *(const short8*)&As[(arow + t * 16) * 32 + acol];
            b[t] = *(const short8*)&Bs[(brow + t * 16) * 32 + acol];
        }
#pragma unroll
        for (int i = 0; i < 4; ++i)
#pragma unroll
            for (int j = 0; j < 4; ++j)
                acc[i][j] = __builtin_amdgcn_mfma_f32_16x16x32_bf16(a[i], b[j], acc[i][j], 0, 0, 0);
        __syncthreads();                 // all reads done before next-tile overwrite
    }

    // epilogue: D row = m0 + wr*64 + i*16 + (l>>4)*4 + rr ; col = n0 + wc*64 + j*16 + (l&15)
    int crow0 = m0 + wr * 64 + ((l >> 4) << 2);
    int ccol0 = n0 + wc * 64 + (l & 15);
#pragma unroll
    for (int i = 0; i < 4; ++i) {
#pragma unroll
        for (int rr = 0; rr < 4; ++rr) {
            int m = crow0 + i * 16 + rr;
            if (m >= M) continue;
            if (flags & 1) {
                bf16* crow = Cb + (long)m * ldc;
#pragma unroll
                for (int j = 0; j < 4; ++j) {
                    int n = ccol0 + j * 16;
                    float v = acc[i][j][rr];
                    if (bias) v += bias[n];
                    v = 0.5f * v * (1.f + erff(v * 0.70710678118654752f));
                    crow[n] = __float2bfloat16(v);
                }
            } else {
                long ro = (long)(m / CR) * CS + (long)((m % CR) + CRoff) * ldc;
                float* crow = Cf + ro;
#pragma unroll
                for (int j = 0; j < 4; ++j) {
                    int n = ccol0 + j * 16;
                    float v = acc[i][j][rr];
                    if (bias) v += bias[n];
                    if (Rz) v += Rz[ro + n];
                    crow[n] = v;
                }
            }
        }
    }
}

// ---------------- attention: flash-decode, 4 waves split the key range ----------------
// grid (qc=4, head=16, b=4), 256 threads. Lane owns query qi = MG + qc*64 + lane.
__global__ __launch_bounds__(256) void attn_k(const float* __restrict__ qkv, bf16* __restrict__ o_mat) {
    int qc = blockIdx.x, head = blockIdx.y, b = blockIdx.z;
    int kvh = head >> 2;
    int tid = threadIdx.x, w = tid >> 6, lane = tid & 63;
    int qi = MG + qc * 64 + lane;
    int nk = MG + qc * 64 + 64;          // keys 0..nk-1
    const float scale = 0.125f;

    float q[64];
    const float* qrow = qkv + ((long)(b * TC + qi) * 1536 + head * DH);
#pragma unroll
    for (int d4 = 0; d4 < 16; ++d4) {
        float4 t = *(const float4*)(qrow + d4 * 4);
        q[d4 * 4 + 0] = t.x * scale; q[d4 * 4 + 1] = t.y * scale;
        q[d4 * 4 + 2] = t.z * scale; q[d4 * 4 + 3] = t.w * scale;
    }
    float o[64];
#pragma unroll
    for (int d = 0; d < 64; ++d) o[d] = 0.f;
    float m = -1e30f, l = 0.f;

    int per = (nk + 3) >> 2;
    int j0 = w * per, j1 = min(j0 + per, nk);
    const float* kbase = qkv + ((long)(b * TC) * 1536 + 1024 + kvh * DH);

    for (int j = j0; j < j1; ++j) {
        const float* kr = kbase + (long)j * 1536;
        float s = 0.f;
#pragma unroll
        for (int d4 = 0; d4 < 16; ++d4) {
            float4 k4 = *(const float4*)(kr + d4 * 4);
            s += q[d4 * 4 + 0] * k4.x + q[d4 * 4 + 1] * k4.y
               + q[d4 * 4 + 2] * k4.z + q[d4 * 4 + 3] * k4.w;
        }
        s = (j <= qi) ? s : -1e30f;
        float mn = fmaxf(m, s);
        float r = __expf(m - mn);
        float p = __expf(s - mn);
        l = l * r + p;
        const float* vr = kr + 256;
#pragma unroll
        for (int d4 = 0; d4 < 16; ++d4) {
            float4 v4 = *(const float4*)(vr + d4 * 4);
            o[d4 * 4 + 0] = o[d4 * 4 + 0] * r + p * v4.x;
            o[d4 * 4 + 1] = o[d4 * 4 + 1] * r + p * v4.y;
            o[d4 * 4 + 2] = o[d4 * 4 + 2] * r + p * v4.z;
            o[d4 * 4 + 3] = o[d4 * 4 + 3] * r + p * v4.w;
        }
        m = mn;
    }

    // merge 4 wave-partials (m,l,o) per query
    __shared__ float sm[4][64], sl[4][64];
    __shared__ float oacc[64][65];
    sm[w][lane] = m; sl[w][lane] = l;
    __syncthreads();
    float M0 = fmaxf(fmaxf(sm[0][lane], sm[1][lane]), fmaxf(sm[2][lane], sm[3][lane]));
    float L = sl[0][lane] * __expf(sm[0][lane] - M0) + sl[1][lane] * __expf(sm[1][lane] - M0)
            + sl[2][lane] * __expf(sm[2][lane] - M0) + sl[3][lane] * __expf(sm[3][lane] - M0);
    float myscale = __expf(m - M0);
#pragma unroll
    for (int t = 0; t < 4; ++t) {
        if (w == t) {
            if (t == 0) {
                for (int d = 0; d < 64; ++d) oacc[lane][d] = o[d] * myscale;
            } else {
                for (int d = 0; d < 64; ++d) oacc[lane][d] += o[d] * myscale;
            }
        }
        __syncthreads();
    }
    float inv = 1.f / L;
    bf16* orow = o_mat + ((long)(b * CHUNK + qc * 64 + lane) * Dm + head * DH + w * 16);
#pragma unroll
    for (int dd = 0; dd < 16; ++dd)
        orow[dd] = __float2bfloat16(oacc[lane][w * 16 + dd] * inv);
}

// mean over 256 chunk rows -> mean_c[b][d]
__global__ __launch_bounds__(256) void col_mean_k(const float* __restrict__ c, long stepOff, float* __restrict__ mean_c) {
    int b = blockIdx.y;
    int d = blockIdx.x * 256 + threadIdx.x;
    const float* base = c + (long)b * TD + stepOff + d;
    float s = 0.f;
    for (int r = 0; r < CHUNK; ++r) s += base[(long)r * Dm];
    mean_c[b * Dm + d] = s * (1.f / CHUNK);
}

// st[b][ss] = mean_c[b] . Wsp[ss] + bsp[ss]
__global__ __launch_bounds__(128) void state_update_k(const float* __restrict__ mean_c, const float* __restrict__ Wsp,
                                                      const float* __restrict__ bsp, float* __restrict__ st) {
    int b = blockIdx.x, ss = threadIdx.x;
    const float* mr = mean_c + b * Dm;
    const float* wr = Wsp + (long)ss * Dm;
    float a = bsp[ss];
#pragma unroll 4
    for (int d = 0; d < Dm; ++d) a += mr[d] * wr[d];
    st[b * SDIM + ss] = a;
}

// ---------------- orchestration ----------------

extern "C" void kernel_launch(void* const* d_in, const int* in_sizes, int n_in,
                              void* d_out, int out_size, void* d_ws, size_t ws_size,
                              hipStream_t stream) {
    const float* x     = (const float*)d_in[0];
    const float* state = (const float*)d_in[1];
    const float* Wq    = (const float*)d_in[2];
    const float* Wk    = (const float*)d_in[3];
    const float* Wv    = (const float*)d_in[4];
    const float* Wo    = (const float*)d_in[5];
    const float* bo    = (const float*)d_in[6];
    const float* lag   = (const float*)d_in[7];
    const float* lab   = (const float*)d_in[8];
    const float* lfg   = (const float*)d_in[9];
    const float* lfb   = (const float*)d_in[10];
    const float* W1    = (const float*)d_in[11];
    const float* b1    = (const float*)d_in[12];
    const float* W2    = (const float*)d_in[13];
    const float* b2    = (const float*)d_in[14];
    const float* Wsp   = (const float*)d_in[15];
    const float* bsp   = (const float*)d_in[16];
    const float* Wsi   = (const float*)d_in[17];
    const float* bsi   = (const float*)d_in[18];
    const float* gtok  = (const float*)d_in[19];

    float* out = (float*)d_out;
    char*  wsb = (char*)d_ws;

    // workspace layout (bytes); qkv/u and o_mat/t_ln are time-aliased
    bf16* wqkv  = (bf16*)(wsb);                       // 1536x1024      (3,145,728 B)
    bf16* wo    = (bf16*)(wsb + 3145728);             // 1024x1024      (2,097,152 B)
    bf16* w1    = (bf16*)(wsb + 5242880);             // 4096x1024      (8,388,608 B)
    bf16* w2    = (bf16*)(wsb + 13631488);            // 1024x4096      (8,388,608 B)
    bf16* h_in  = (bf16*)(wsb + 22020096);            // 1152x1024 rows (2,359,296 B) [96 pad rows]
    char* scrA  = wsb + 24379392;                      // max(qkv f32 6.49MB, u bf16 8.39MB)
    float* qkv  = (float*)scrA;                        // 1056x1536 f32
    bf16*  u    = (bf16*)scrA;                         // 1024x4096 bf16
    char* scrB  = wsb + 32768000;                      // max(o_mat, t_ln) bf16 1024x1024
    bf16* o_mat = (bf16*)scrB;
    bf16* t_ln  = (bf16*)scrB;
    float* si     = (float*)(wsb + 34865152);          // 4096 f32
    float* mean_c = (float*)(wsb + 34881536);          // 4096 f32
    float* st     = (float*)(wsb + 34897920);          // 512 f32

    // ---- setup: state copy, weight conversion, global-token rows ----
    vcopy_k<<<1, 512, 0, stream>>>(state, st, 512);
    cvt_bf16_k<<<1024, 256, 0, stream>>>(Wq, wqkv,            262144);
    cvt_bf16_k<<< 256, 256, 0, stream>>>(Wk, wqkv + 1048576,   65536);
    cvt_bf16_k<<< 256, 256, 0, stream>>>(Wv, wqkv + 1310720,   65536);
    cvt_bf16_k<<<1024, 256, 0, stream>>>(Wo, wo,              262144);
    cvt_bf16_k<<<4096, 256, 0, stream>>>(W1, w1,             1048576);
    cvt_bf16_k<<<4096, 256, 0, stream>>>(W2, w2,             1048576);
    fill_globals_k<<<128, 256, 0, stream>>>(gtok, h_in);

    for (int s = 0; s < NSTEP; ++s) {
        long roff = (long)s * CHUNK;           // row offset within a batch of out/x
        state_proj_k<<<16, 256, 0, stream>>>(st, Wsi, bsi, si);
        // attn LN -> h_in rows MG..263 (bf16)
        ln_rows_k<<<dim3(256, 4), 256, 0, stream>>>(x, TD, roff, h_in, (long)TC * Dm, MG, lag, lab, si);
        // QKV: [1056 x 1536 x 1024] -> qkv f32 contiguous
        gemm_bf16<<<dim3(12, 9), 256, 0, stream>>>(
            h_in, wqkv, Bn * TC, 1536, 1024,
            qkv, nullptr, nullptr, nullptr,
            1 << 30, 0L, 0L, 1536, 0);
        attn_k<<<dim3(4, 16, 4), 256, 0, stream>>>(qkv, o_mat);
        // Wo + bo + residual(x chunk) -> out chunk (c_pre, f32)
        gemm_bf16<<<dim3(8, 8), 256, 0, stream>>>(
            o_mat, wo, Bn * CHUNK, 1024, 1024,
            out, x, nullptr, bo,
            CHUNK, TD, roff, Dm, 0);
        // ffn LN -> t_ln bf16
        ln_rows_k<<<dim3(256, 4), 256, 0, stream>>>(out, TD, roff, t_ln, (long)CHUNK * Dm, 0, lfg, lfb, nullptr);
        // FFN1 + gelu -> u bf16
        gemm_bf16<<<dim3(32, 8), 256, 0, stream>>>(
            t_ln, w1, Bn * CHUNK, 4096, 1024,
            nullptr, nullptr, u, b1,
            1 << 30, 0L, 0L, 4096, 1);
        // FFN2 + b2 + residual(c_pre) -> out chunk (final c)
        gemm_bf16<<<dim3(8, 8), 256, 0, stream>>>(
            u, w2, Bn * CHUNK, 1024, 4096,
            out, out, nullptr, b2,
            CHUNK, TD, roff, Dm, 0);
        // state update
        col_mean_k<<<dim3(4, 4), 256, 0, stream>>>(out, roff * Dm, mean_c);
        state_update_k<<<4, 128, 0, stream>>>(mean_c, Wsp, bsp, st);
    }
    vcopy_k<<<1, 512, 0, stream>>>(st, out + (long)Bn * Tn * Dm, 512);
}

// Round 3
// 4914.774 us; speedup vs baseline: 2.2898x; 1.3570x over previous
//
#include <hip/hip_runtime.h>
#include <hip/hip_bf16.h>

// Sizes
#define Dm    1024
#define Hn    16
#define KVH   4
#define DH    64
#define CHUNK 256
#define SDIM  128
#define MG    8
#define Bn    4
#define Tn    4096
#define TC    264            // MG + CHUNK
#define NSTEP 16
#define TD    4194304L       // Tn*Dm per batch

typedef __attribute__((ext_vector_type(8))) short short8;
typedef __attribute__((ext_vector_type(4))) float floatx4;
typedef __hip_bfloat16 bf16;

__device__ __forceinline__ void gl16(const void* g, void* l) {
    using GP = const __attribute__((address_space(1))) char*;
    using LP = __attribute__((address_space(3))) char*;
    __builtin_amdgcn_global_load_lds((GP)g, (LP)l, 16, 0, 0);
}

// ---------------- utility kernels ----------------

__global__ __launch_bounds__(512) void vcopy_k(const float* __restrict__ s, float* __restrict__ d, int n) {
    int i = blockIdx.x * 512 + threadIdx.x;
    if (i < n) d[i] = s[i];
}

__global__ __launch_bounds__(256) void cvt_bf16_k(const float* __restrict__ s, bf16* __restrict__ d, int n4) {
    int i = blockIdx.x * 256 + threadIdx.x;
    if (i >= n4) return;
    float4 v = ((const float4*)s)[i];
    bf16* o = d + i * 4;
    o[0] = __float2bfloat16(v.x); o[1] = __float2bfloat16(v.y);
    o[2] = __float2bfloat16(v.z); o[3] = __float2bfloat16(v.w);
}

__global__ __launch_bounds__(256) void fill_globals_k(const float* __restrict__ gtok, bf16* __restrict__ h_in) {
    int idx = blockIdx.x * 256 + threadIdx.x;      // 0..32767  (4 b * 8 rows * 1024)
    int b = idx >> 13, rd = idx & 8191;
    h_in[(long)b * (TC * Dm) + rd] = __float2bfloat16(gtok[rd]);
}

// si[b][d] = sum_s st[b][s] * Wsi[d][s] + bsi[d]
__global__ __launch_bounds__(256) void state_proj_k(const float* __restrict__ st, const float* __restrict__ Wsi,
                                                    const float* __restrict__ bsi, float* __restrict__ si) {
    int idx = blockIdx.x * 256 + threadIdx.x;      // 0..4095
    int b = idx >> 10, d = idx & 1023;
    const float* sr = st + b * SDIM;
    const float* wr = Wsi + (long)d * SDIM;
    float a = bsi[d];
#pragma unroll 4
    for (int k = 0; k < SDIM; ++k) a += sr[k] * wr[k];
    si[idx] = a;
}

// LayerNorm of one 1024-row per block; optional per-batch add vector (si). bf16 output.
__global__ __launch_bounds__(256) void ln_rows_k(const float* __restrict__ in, long inS, long inRoff,
                                                 bf16* __restrict__ out, long outS, long outRoff,
                                                 const float* __restrict__ g, const float* __restrict__ be,
                                                 const float* __restrict__ add) {
    int r = blockIdx.x, b = blockIdx.y, tid = threadIdx.x;
    const float* row = in + (long)b * inS + (inRoff + r) * (long)Dm;
    float4 v = *(const float4*)(row + tid * 4);
    float s = v.x + v.y + v.z + v.w;
    float q = v.x * v.x + v.y * v.y + v.z * v.z + v.w * v.w;
    for (int off = 32; off > 0; off >>= 1) { s += __shfl_down(s, off); q += __shfl_down(q, off); }
    __shared__ float red[10];
    int w = tid >> 6;
    if ((tid & 63) == 0) { red[w] = s; red[4 + w] = q; }
    __syncthreads();
    if (tid == 0) {
        float ts = red[0] + red[1] + red[2] + red[3];
        float tq = red[4] + red[5] + red[6] + red[7];
        float mean = ts * (1.f / Dm);
        float var = tq * (1.f / Dm) - mean * mean;
        red[8] = mean;
        red[9] = rsqrtf(var + 1e-5f);
    }
    __syncthreads();
    float mean = red[8], rstd = red[9];
    int d = tid * 4;
    float4 gv = *(const float4*)(g + d);
    float4 bv = *(const float4*)(be + d);
    float o0 = (v.x - mean) * rstd * gv.x + bv.x;
    float o1 = (v.y - mean) * rstd * gv.y + bv.y;
    float o2 = (v.z - mean) * rstd * gv.z + bv.z;
    float o3 = (v.w - mean) * rstd * gv.w + bv.w;
    if (add) {
        float4 av = *(const float4*)(add + b * Dm + d);
        o0 += av.x; o1 += av.y; o2 += av.z; o3 += av.w;
    }
    bf16* orow = out + (long)b * outS + (outRoff + r) * (long)Dm + d;
    orow[0] = __float2bfloat16(o0); orow[1] = __float2bfloat16(o1);
    orow[2] = __float2bfloat16(o2); orow[3] = __float2bfloat16(o3);
}

// ---------------- bf16 MFMA GEMM:  C = act(A @ W^T + bias + residual) ----------------
// flags: bit0 = bf16 out via Cb (contiguous ldc); bit1 = GELU. Else f32 out via
// row-mapped Cf (CR/CS/CRoff/ldc) + optional bias + optional residual Rz (same mapping).
__global__ __launch_bounds__(256) void gemm_bf16(
    const bf16* __restrict__ A, const bf16* __restrict__ W,
    int M, int N, int K,
    float* __restrict__ Cf, const float* __restrict__ Rz,
    bf16* __restrict__ Cb, const float* __restrict__ bias,
    int CR, long CS, long CRoff, int ldc, int flags)
{
    __shared__ short As[128 * 32];
    __shared__ short Bs[128 * 32];
    int tid = threadIdx.x;
    int w = tid >> 6, l = tid & 63;
    int wr = w >> 1, wc = w & 1;
    int m0 = blockIdx.y << 7, n0 = blockIdx.x << 7;

    int r0 = w * 16 + (l >> 2);          // row for seg w
    int kc = (l & 3) << 3;               // k elem offset (8 bf16 = 16B)
    const bf16* pA0 = A + (long)(m0 + r0) * K + kc;
    const bf16* pA1 = pA0 + (long)64 * K;
    const bf16* pW0 = W + (long)(n0 + r0) * K + kc;
    const bf16* pW1 = pW0 + (long)64 * K;
    char* lA0 = (char*)As + w * 1024 + l * 16;
    char* lA1 = (char*)As + 4096 + w * 1024 + l * 16;
    char* lB0 = (char*)Bs + w * 1024 + l * 16;
    char* lB1 = (char*)Bs + 4096 + w * 1024 + l * 16;

    floatx4 acc[4][4];
#pragma unroll
    for (int i = 0; i < 4; ++i)
#pragma unroll
        for (int j = 0; j < 4; ++j) acc[i][j] = (floatx4){0.f, 0.f, 0.f, 0.f};

    int arow = wr * 64 + (l & 15);
    int brow = wc * 64 + (l & 15);
    int acol = (l >> 4) << 3;

    for (int kt = 0; kt < K; kt += 32) {
        gl16(pA0 + kt, lA0);
        gl16(pA1 + kt, lA1);
        gl16(pW0 + kt, lB0);
        gl16(pW1 + kt, lB1);
        __syncthreads();
        short8 a[4], b[4];
#pragma unroll
        for (int t = 0; t < 4; ++t) {
            a[t] = *(const short8*)&As[(arow + t * 16) * 32 + acol];
            b[t] = *(const short8*)&Bs[(brow + t * 16) * 32 + acol];
        }
#pragma unroll
        for (int i = 0; i < 4; ++i)
#pragma unroll
            for (int j = 0; j < 4; ++j)
                acc[i][j] = __builtin_amdgcn_mfma_f32_16x16x32_bf16(a[i], b[j], acc[i][j], 0, 0, 0);
        __syncthreads();
    }

    int crow0 = m0 + wr * 64 + ((l >> 4) << 2);
    int ccol0 = n0 + wc * 64 + (l & 15);
#pragma unroll
    for (int i = 0; i < 4; ++i) {
#pragma unroll
        for (int rr = 0; rr < 4; ++rr) {
            int m = crow0 + i * 16 + rr;
            if (m >= M) continue;
            if (flags & 1) {
                bf16* crow = Cb + (long)m * ldc;
#pragma unroll
                for (int j = 0; j < 4; ++j) {
                    int n = ccol0 + j * 16;
                    float v = acc[i][j][rr];
                    if (bias) v += bias[n];
                    if (flags & 2) v = 0.5f * v * (1.f + erff(v * 0.70710678118654752f));
                    crow[n] = __float2bfloat16(v);
                }
            } else {
                long ro = (long)(m / CR) * CS + (long)((m % CR) + CRoff) * ldc;
                float* crow = Cf + ro;
#pragma unroll
                for (int j = 0; j < 4; ++j) {
                    int n = ccol0 + j * 16;
                    float v = acc[i][j][rr];
                    if (bias) v += bias[n];
                    if (Rz) v += Rz[ro + n];
                    crow[n] = v;
                }
            }
        }
    }
}

// ---------------- attention: MFMA flash, 4 waves x 16 queries ----------------
// grid (qc=4, head=16, b=4), 256 threads. Block: queries [8+qc*64, 8+qc*64+64),
// keys 0..(qc+2)*64-1 in tiles of 64, causal-masked. bf16 QK/PV, f32 softmax.
__global__ __launch_bounds__(256) void attn_mfma_k(const bf16* __restrict__ qkv, bf16* __restrict__ o_mat) {
    int qc = blockIdx.x, head = blockIdx.y, b = blockIdx.z;
    int kvh = head >> 2;
    int tid = threadIdx.x, w = tid >> 6, l = tid & 63;
    int m16 = l & 15, h4 = l >> 4;

    __shared__ short Qs[64][64];
    __shared__ short Ks[64][64];
    __shared__ short Vt[64][64];           // [dim][key]
    __shared__ short Ps[4][16][64];        // per-wave P tile [q][key]

    const long rowq0 = (long)b * TC + MG + qc * 64;
    const bf16* kbase = qkv + ((long)b * TC) * 1536 + 1024 + kvh * DH;
    const bf16* vbase = kbase + 256;

    // stage Q (64 rows x 64 dims) via global_load_lds: lds addr = base + lane*16
#pragma unroll
    for (int p = 0; p < 2; ++p) {
        int rr = p * 32 + (tid >> 3);
        gl16(qkv + (rowq0 + rr) * 1536 + head * DH + (tid & 7) * 8, &Qs[rr][(tid & 7) * 8]);
    }

    float a_m[4] = {-1e30f, -1e30f, -1e30f, -1e30f};
    float a_l[4] = {0.f, 0.f, 0.f, 0.f};
    floatx4 acc_o[4];
#pragma unroll
    for (int dt = 0; dt < 4; ++dt) acc_o[dt] = (floatx4){0.f, 0.f, 0.f, 0.f};
    short8 aq[2];

    int qtok0 = MG + qc * 64 + w * 16 + h4 * 4;   // token index of this lane's reg-row 0
    int ntiles = qc + 2;

    for (int t = 0; t < ntiles; ++t) {
        int jt = t * 64;
        // stage K tile via gl16 (clamped rows; invalid keys masked later)
#pragma unroll
        for (int p = 0; p < 2; ++p) {
            int rr = p * 32 + (tid >> 3);
            int gk = min(jt + rr, TC - 1);
            gl16(kbase + (long)gk * 1536 + (tid & 7) * 8, &Ks[rr][(tid & 7) * 8]);
        }
        // stage V transposed: lane l owns key row jt+l, writes Vt[d][l]
#pragma unroll
        for (int p = 0; p < 2; ++p) {
            int cg = p * 4 + w;
            int gk = min(jt + l, TC - 1);
            short8 vv = *(const short8*)(vbase + (long)gk * 1536 + cg * 8);
#pragma unroll
            for (int e = 0; e < 8; ++e) Vt[cg * 8 + e][l] = vv[e];
        }
        __syncthreads();
        if (t == 0) {
            aq[0] = *(const short8*)&Qs[w * 16 + m16][h4 * 8];
            aq[1] = *(const short8*)&Qs[w * 16 + m16][32 + h4 * 8];
        }
        // S = Q.K^T (16q x 64k per wave)
        floatx4 s[4];
#pragma unroll
        for (int st = 0; st < 4; ++st) {
            s[st] = (floatx4){0.f, 0.f, 0.f, 0.f};
#pragma unroll
            for (int c = 0; c < 2; ++c) {
                short8 kf = *(const short8*)&Ks[st * 16 + m16][c * 32 + h4 * 8];
                s[st] = __builtin_amdgcn_mfma_f32_16x16x32_bf16(aq[c], kf, s[st], 0, 0, 0);
            }
        }
        // scale + causal mask
#pragma unroll
        for (int st = 0; st < 4; ++st) {
            int keyg = jt + st * 16 + m16;
#pragma unroll
            for (int r = 0; r < 4; ++r) {
                float v = s[st][r] * 0.125f;
                s[st][r] = (keyg > qtok0 + r) ? -1e30f : v;
            }
        }
        // online softmax (per q-row: reduce across 16 lanes of same h4-group)
#pragma unroll
        for (int r = 0; r < 4; ++r) {
            float tm = fmaxf(fmaxf(s[0][r], s[1][r]), fmaxf(s[2][r], s[3][r]));
            tm = fmaxf(tm, __shfl_xor(tm, 1));
            tm = fmaxf(tm, __shfl_xor(tm, 2));
            tm = fmaxf(tm, __shfl_xor(tm, 4));
            tm = fmaxf(tm, __shfl_xor(tm, 8));
            float mn = fmaxf(a_m[r], tm);
            float rs = __expf(a_m[r] - mn);
            a_m[r] = mn;
            float ps = 0.f;
#pragma unroll
            for (int st = 0; st < 4; ++st) {
                float p = __expf(s[st][r] - mn);
                s[st][r] = p;
                ps += p;
            }
            ps += __shfl_xor(ps, 1); ps += __shfl_xor(ps, 2);
            ps += __shfl_xor(ps, 4); ps += __shfl_xor(ps, 8);
            a_l[r] = a_l[r] * rs + ps;
#pragma unroll
            for (int dt = 0; dt < 4; ++dt) acc_o[dt][r] *= rs;
#pragma unroll
            for (int st = 0; st < 4; ++st) {
                bf16 hb = __float2bfloat16(s[st][r]);
                Ps[w][h4 * 4 + r][st * 16 + m16] = *reinterpret_cast<short*>(&hb);
            }
        }
        // O += P.V  (A-frag from Ps, B-frag from Vt)
#pragma unroll
        for (int c = 0; c < 2; ++c) {
            short8 ap = *(const short8*)&Ps[w][m16][c * 32 + h4 * 8];
#pragma unroll
            for (int dt = 0; dt < 4; ++dt) {
                short8 vf = *(const short8*)&Vt[dt * 16 + m16][c * 32 + h4 * 8];
                acc_o[dt] = __builtin_amdgcn_mfma_f32_16x16x32_bf16(ap, vf, acc_o[dt], 0, 0, 0);
            }
        }
        __syncthreads();
    }

    // epilogue: row = qc*64 + w*16 + h4*4 + r (chunk-local), col = head*64 + dt*16 + m16
#pragma unroll
    for (int r = 0; r < 4; ++r) {
        float inv = 1.f / a_l[r];
        long row = (long)b * CHUNK + qc * 64 + w * 16 + h4 * 4 + r;
#pragma unroll
        for (int dt = 0; dt < 4; ++dt)
            o_mat[row * Dm + head * DH + dt * 16 + m16] = __float2bfloat16(acc_o[dt][r] * inv);
    }
}

// mean over 256 chunk rows -> mean_c[b][d]
__global__ __launch_bounds__(256) void col_mean_k(const float* __restrict__ c, long stepOff, float* __restrict__ mean_c) {
    int b = blockIdx.y;
    int d = blockIdx.x * 256 + threadIdx.x;
    const float* base = c + (long)b * TD + stepOff + d;
    float s = 0.f;
    for (int r = 0; r < CHUNK; ++r) s += base[(long)r * Dm];
    mean_c[b * Dm + d] = s * (1.f / CHUNK);
}

// st[b][ss] = mean_c[b] . Wsp[ss] + bsp[ss]
__global__ __launch_bounds__(128) void state_update_k(const float* __restrict__ mean_c, const float* __restrict__ Wsp,
                                                      const float* __restrict__ bsp, float* __restrict__ st) {
    int b = blockIdx.x, ss = threadIdx.x;
    const float* mr = mean_c + b * Dm;
    const float* wr = Wsp + (long)ss * Dm;
    float a = bsp[ss];
#pragma unroll 4
    for (int d = 0; d < Dm; ++d) a += mr[d] * wr[d];
    st[b * SDIM + ss] = a;
}

// ---------------- orchestration ----------------

extern "C" void kernel_launch(void* const* d_in, const int* in_sizes, int n_in,
                              void* d_out, int out_size, void* d_ws, size_t ws_size,
                              hipStream_t stream) {
    const float* x     = (const float*)d_in[0];
    const float* state = (const float*)d_in[1];
    const float* Wq    = (const float*)d_in[2];
    const float* Wk    = (const float*)d_in[3];
    const float* Wv    = (const float*)d_in[4];
    const float* Wo    = (const float*)d_in[5];
    const float* bo    = (const float*)d_in[6];
    const float* lag   = (const float*)d_in[7];
    const float* lab   = (const float*)d_in[8];
    const float* lfg   = (const float*)d_in[9];
    const float* lfb   = (const float*)d_in[10];
    const float* W1    = (const float*)d_in[11];
    const float* b1    = (const float*)d_in[12];
    const float* W2    = (const float*)d_in[13];
    const float* b2    = (const float*)d_in[14];
    const float* Wsp   = (const float*)d_in[15];
    const float* bsp   = (const float*)d_in[16];
    const float* Wsi   = (const float*)d_in[17];
    const float* bsi   = (const float*)d_in[18];
    const float* gtok  = (const float*)d_in[19];

    float* out = (float*)d_out;
    char*  wsb = (char*)d_ws;

    // workspace layout (bytes); qkv/u and o_mat/t_ln are time-aliased
    bf16* wqkv  = (bf16*)(wsb);                       // 1536x1024      (3,145,728 B)
    bf16* wo    = (bf16*)(wsb + 3145728);             // 1024x1024      (2,097,152 B)
    bf16* w1    = (bf16*)(wsb + 5242880);             // 4096x1024      (8,388,608 B)
    bf16* w2    = (bf16*)(wsb + 13631488);            // 1024x4096      (8,388,608 B)
    bf16* h_in  = (bf16*)(wsb + 22020096);            // 1152x1024 rows (2,359,296 B) [96 pad rows]
    char* scrA  = wsb + 24379392;                      // max(qkv bf16 3.24MB, u bf16 8.39MB)
    bf16* qkvb  = (bf16*)scrA;                         // 1056x1536 bf16
    bf16* u     = (bf16*)scrA;                         // 1024x4096 bf16
    char* scrB  = wsb + 32768000;                      // max(o_mat, t_ln) bf16 1024x1024
    bf16* o_mat = (bf16*)scrB;
    bf16* t_ln  = (bf16*)scrB;
    float* si     = (float*)(wsb + 34865152);          // 4096 f32
    float* mean_c = (float*)(wsb + 34881536);          // 4096 f32
    float* st     = (float*)(wsb + 34897920);          // 512 f32

    // ---- setup: state copy, weight conversion, global-token rows ----
    vcopy_k<<<1, 512, 0, stream>>>(state, st, 512);
    cvt_bf16_k<<<1024, 256, 0, stream>>>(Wq, wqkv,            262144);
    cvt_bf16_k<<< 256, 256, 0, stream>>>(Wk, wqkv + 1048576,   65536);
    cvt_bf16_k<<< 256, 256, 0, stream>>>(Wv, wqkv + 1310720,   65536);
    cvt_bf16_k<<<1024, 256, 0, stream>>>(Wo, wo,              262144);
    cvt_bf16_k<<<4096, 256, 0, stream>>>(W1, w1,             1048576);
    cvt_bf16_k<<<4096, 256, 0, stream>>>(W2, w2,             1048576);
    fill_globals_k<<<128, 256, 0, stream>>>(gtok, h_in);

    for (int s = 0; s < NSTEP; ++s) {
        long roff = (long)s * CHUNK;           // row offset within a batch of out/x
        state_proj_k<<<16, 256, 0, stream>>>(st, Wsi, bsi, si);
        // attn LN -> h_in rows MG..263 (bf16)
        ln_rows_k<<<dim3(256, 4), 256, 0, stream>>>(x, TD, roff, h_in, (long)TC * Dm, MG, lag, lab, si);
        // QKV: [1056 x 1536 x 1024] -> qkvb bf16 contiguous
        gemm_bf16<<<dim3(12, 9), 256, 0, stream>>>(
            h_in, wqkv, Bn * TC, 1536, 1024,
            nullptr, nullptr, qkvb, nullptr,
            1 << 30, 0L, 0L, 1536, 1);
        attn_mfma_k<<<dim3(4, 16, 4), 256, 0, stream>>>(qkvb, o_mat);
        // Wo + bo + residual(x chunk) -> out chunk (c_pre, f32)
        gemm_bf16<<<dim3(8, 8), 256, 0, stream>>>(
            o_mat, wo, Bn * CHUNK, 1024, 1024,
            out, x, nullptr, bo,
            CHUNK, TD, roff, Dm, 0);
        // ffn LN -> t_ln bf16
        ln_rows_k<<<dim3(256, 4), 256, 0, stream>>>(out, TD, roff, t_ln, (long)CHUNK * Dm, 0, lfg, lfb, nullptr);
        // FFN1 + gelu -> u bf16
        gemm_bf16<<<dim3(32, 8), 256, 0, stream>>>(
            t_ln, w1, Bn * CHUNK, 4096, 1024,
            nullptr, nullptr, u, b1,
            1 << 30, 0L, 0L, 4096, 3);
        // FFN2 + b2 + residual(c_pre) -> out chunk (final c)
        gemm_bf16<<<dim3(8, 8), 256, 0, stream>>>(
            u, w2, Bn * CHUNK, 1024, 4096,
            out, out, nullptr, b2,
            CHUNK, TD, roff, Dm, 0);
        // state update
        col_mean_k<<<dim3(4, 4), 256, 0, stream>>>(out, roff * Dm, mean_c);
        state_update_k<<<4, 128, 0, stream>>>(mean_c, Wsp, bsp, st);
    }
    vcopy_k<<<1, 512, 0, stream>>>(st, out + (long)Bn * Tn * Dm, 512);
}

// Round 4
// 3287.554 us; speedup vs baseline: 3.4232x; 1.4950x over previous
//
#include <hip/hip_runtime.h>
#include <hip/hip_bf16.h>

// Sizes
#define Dm    1024
#define Hn    16
#define KVH   4
#define DH    64
#define CHUNK 256
#define SDIM  128
#define MG    8
#define Bn    4
#define Tn    4096
#define TC    264            // MG + CHUNK
#define NSTEP 16
#define TD    4194304L       // Tn*Dm per batch

typedef __attribute__((ext_vector_type(8))) short short8;
typedef __attribute__((ext_vector_type(4))) float floatx4;
typedef __hip_bfloat16 bf16;

__device__ __forceinline__ void gl16(const void* g, void* l) {
    using GP = const __attribute__((address_space(1))) char*;
    using LP = __attribute__((address_space(3))) char*;
    __builtin_amdgcn_global_load_lds((GP)g, (LP)l, 16, 0, 0);
}

// ---------------- utility kernels ----------------

__global__ __launch_bounds__(512) void vcopy_k(const float* __restrict__ s, float* __restrict__ d, int n) {
    int i = blockIdx.x * 512 + threadIdx.x;
    if (i < n) d[i] = s[i];
}

__global__ __launch_bounds__(256) void cvt_bf16_k(const float* __restrict__ s, bf16* __restrict__ d, int n4) {
    int i = blockIdx.x * 256 + threadIdx.x;
    if (i >= n4) return;
    float4 v = ((const float4*)s)[i];
    bf16* o = d + i * 4;
    o[0] = __float2bfloat16(v.x); o[1] = __float2bfloat16(v.y);
    o[2] = __float2bfloat16(v.z); o[3] = __float2bfloat16(v.w);
}

__global__ __launch_bounds__(256) void fill_globals_k(const float* __restrict__ gtok, bf16* __restrict__ h_in) {
    int idx = blockIdx.x * 256 + threadIdx.x;      // 0..32767  (4 b * 8 rows * 1024)
    int b = idx >> 13, rd = idx & 8191;
    h_in[(long)b * (TC * Dm) + rd] = __float2bfloat16(gtok[rd]);
}

// si[b][d] = sum_s st[b][s] * Wsi[d][s] + bsi[d]
__global__ __launch_bounds__(256) void state_proj_k(const float* __restrict__ st, const float* __restrict__ Wsi,
                                                    const float* __restrict__ bsi, float* __restrict__ si) {
    int idx = blockIdx.x * 256 + threadIdx.x;      // 0..4095
    int b = idx >> 10, d = idx & 1023;
    const float* sr = st + b * SDIM;
    const float* wr = Wsi + (long)d * SDIM;
    float a = bsi[d];
#pragma unroll 4
    for (int k = 0; k < SDIM; ++k) a += sr[k] * wr[k];
    si[idx] = a;
}

// LayerNorm of one 1024-row per block; optional per-batch add vector (si). bf16 output.
__global__ __launch_bounds__(256) void ln_rows_k(const float* __restrict__ in, long inS, long inRoff,
                                                 bf16* __restrict__ out, long outS, long outRoff,
                                                 const float* __restrict__ g, const float* __restrict__ be,
                                                 const float* __restrict__ add) {
    int r = blockIdx.x, b = blockIdx.y, tid = threadIdx.x;
    const float* row = in + (long)b * inS + (inRoff + r) * (long)Dm;
    float4 v = *(const float4*)(row + tid * 4);
    float s = v.x + v.y + v.z + v.w;
    float q = v.x * v.x + v.y * v.y + v.z * v.z + v.w * v.w;
    for (int off = 32; off > 0; off >>= 1) { s += __shfl_down(s, off); q += __shfl_down(q, off); }
    __shared__ float red[10];
    int w = tid >> 6;
    if ((tid & 63) == 0) { red[w] = s; red[4 + w] = q; }
    __syncthreads();
    if (tid == 0) {
        float ts = red[0] + red[1] + red[2] + red[3];
        float tq = red[4] + red[5] + red[6] + red[7];
        float mean = ts * (1.f / Dm);
        float var = tq * (1.f / Dm) - mean * mean;
        red[8] = mean;
        red[9] = rsqrtf(var + 1e-5f);
    }
    __syncthreads();
    float mean = red[8], rstd = red[9];
    int d = tid * 4;
    float4 gv = *(const float4*)(g + d);
    float4 bv = *(const float4*)(be + d);
    float o0 = (v.x - mean) * rstd * gv.x + bv.x;
    float o1 = (v.y - mean) * rstd * gv.y + bv.y;
    float o2 = (v.z - mean) * rstd * gv.z + bv.z;
    float o3 = (v.w - mean) * rstd * gv.w + bv.w;
    if (add) {
        float4 av = *(const float4*)(add + b * Dm + d);
        o0 += av.x; o1 += av.y; o2 += av.z; o3 += av.w;
    }
    bf16* orow = out + (long)b * outS + (outRoff + r) * (long)Dm + d;
    orow[0] = __float2bfloat16(o0); orow[1] = __float2bfloat16(o1);
    orow[2] = __float2bfloat16(o2); orow[3] = __float2bfloat16(o3);
}

// ---------------- bf16 MFMA GEMM, 2-stage pipelined, optional split-K ----------------
// A: [Mpad][K] bf16 row-major. W: [N][K] bf16 row-major. K-range per block-z:
// [z*kspan, (z+1)*kspan). If Cpart: raw f32 partial to Cpart + z*partMN + m*N + n.
// Else: bf16 out Cb[m*ldc+n] (+bias, optional exact GELU).
__global__ __launch_bounds__(256) void gemm_bf16(
    const bf16* __restrict__ A, const bf16* __restrict__ W,
    int M, int N, int K, int kspan,
    bf16* __restrict__ Cb, int ldc, const float* __restrict__ bias, int gelu,
    float* __restrict__ Cpart, long partMN)
{
    __shared__ short As[2][4096];
    __shared__ short Bs[2][4096];
    int tid = threadIdx.x;
    int w = tid >> 6, l = tid & 63;
    int wr = w >> 1, wc = w & 1;
    int m0 = blockIdx.y << 7, n0 = blockIdx.x << 7;
    int kb = blockIdx.z * kspan;

    int r0 = w * 16 + (l >> 2);          // staged row for this lane (seg w)
    int kc = (l & 3) << 3;               // k elem offset (8 bf16 = 16B)
    const bf16* pA0 = A + (long)(m0 + r0) * K + kc + kb;
    const bf16* pA1 = pA0 + (long)64 * K;
    const bf16* pW0 = W + (long)(n0 + r0) * K + kc + kb;
    const bf16* pW1 = pW0 + (long)64 * K;
    int lofs = w * 1024 + l * 16;        // byte offset of this lane's 16B slot
    char* cA = (char*)As;
    char* cB = (char*)Bs;

    floatx4 acc[4][4];
#pragma unroll
    for (int i = 0; i < 4; ++i)
#pragma unroll
        for (int j = 0; j < 4; ++j) acc[i][j] = (floatx4){0.f, 0.f, 0.f, 0.f};

    int arow = wr * 64 + (l & 15);
    int brow = wc * 64 + (l & 15);
    int acol = (l >> 4) << 3;

    int nk = kspan >> 5;
    // prologue: stage tile 0 into buf 0
    gl16(pA0, cA + lofs);
    gl16(pA1, cA + 4096 + lofs);
    gl16(pW0, cB + lofs);
    gl16(pW1, cB + 4096 + lofs);

    int cur = 0;
    for (int i = 0; i < nk; ++i) {
        if (i + 1 < nk) {
            int kt = (i + 1) << 5;
            int bo = (cur ^ 1) * 8192;
            gl16(pA0 + kt, cA + bo + lofs);
            gl16(pA1 + kt, cA + bo + 4096 + lofs);
            gl16(pW0 + kt, cB + bo + lofs);
            gl16(pW1 + kt, cB + bo + 4096 + lofs);
            asm volatile("s_waitcnt vmcnt(4)" ::: "memory");   // my cur-tile loads done
        } else {
            asm volatile("s_waitcnt vmcnt(0)" ::: "memory");
        }
        __builtin_amdgcn_s_barrier();                           // all waves' cur-tile in LDS
        __builtin_amdgcn_sched_barrier(0);
        const short* Ab = As[cur];
        const short* Bb = Bs[cur];
        short8 a[4], b[4];
#pragma unroll
        for (int t = 0; t < 4; ++t) {
            a[t] = *(const short8*)&Ab[(arow + t * 16) * 32 + acol];
            b[t] = *(const short8*)&Bb[(brow + t * 16) * 32 + acol];
        }
#pragma unroll
        for (int ii = 0; ii < 4; ++ii)
#pragma unroll
            for (int jj = 0; jj < 4; ++jj)
                acc[ii][jj] = __builtin_amdgcn_mfma_f32_16x16x32_bf16(a[ii], b[jj], acc[ii][jj], 0, 0, 0);
        __builtin_amdgcn_sched_barrier(0);
        __builtin_amdgcn_s_barrier();                           // reads done before next overwrite
        cur ^= 1;
    }

    // epilogue: D row = m0 + wr*64 + i*16 + (l>>4)*4 + rr ; col = n0 + wc*64 + j*16 + (l&15)
    int crow0 = m0 + wr * 64 + ((l >> 4) << 2);
    int ccol0 = n0 + wc * 64 + (l & 15);
    if (Cpart) {
        float* pp = Cpart + (long)blockIdx.z * partMN;
#pragma unroll
        for (int i = 0; i < 4; ++i)
#pragma unroll
            for (int rr = 0; rr < 4; ++rr) {
                int m = crow0 + i * 16 + rr;
                if (m >= M) continue;
#pragma unroll
                for (int j = 0; j < 4; ++j)
                    pp[(long)m * N + ccol0 + j * 16] = acc[i][j][rr];
            }
    } else {
#pragma unroll
        for (int i = 0; i < 4; ++i)
#pragma unroll
            for (int rr = 0; rr < 4; ++rr) {
                int m = crow0 + i * 16 + rr;
                if (m >= M) continue;
                bf16* crow = Cb + (long)m * ldc;
#pragma unroll
                for (int j = 0; j < 4; ++j) {
                    int n = ccol0 + j * 16;
                    float v = acc[i][j][rr];
                    if (bias) v += bias[n];
                    if (gelu) v = 0.5f * v * (1.f + erff(v * 0.70710678118654752f));
                    crow[n] = __float2bfloat16(v);
                }
            }
    }
}

// ---------------- split-K reduce: out[map(m,n)] = sum_z part[z] + bias + res ----------------
// M=1024 rows (4 batches x 256 chunk rows), N=1024. res/out mapped via roff.
__global__ __launch_bounds__(256) void reduce_splitk_k(const float* __restrict__ part, int KS,
                                                       const float* __restrict__ bias,
                                                       const float* __restrict__ res,
                                                       float* __restrict__ out, long roff) {
    int e4 = blockIdx.x * 256 + threadIdx.x;        // 0..262143 (float4 elements)
    int m = e4 >> 8, n4 = e4 & 255;
    float4 s = ((const float4*)part)[e4];
    for (int z = 1; z < KS; ++z) {
        float4 p = ((const float4*)(part + (long)z * 1048576))[e4];
        s.x += p.x; s.y += p.y; s.z += p.z; s.w += p.w;
    }
    float4 bv = ((const float4*)bias)[n4];
    long ro = (long)(m >> 8) * TD + (roff + (m & 255)) * 1024L + n4 * 4;
    float4 rv = *(const float4*)(res + ro);
    s.x += bv.x + rv.x; s.y += bv.y + rv.y; s.z += bv.z + rv.z; s.w += bv.w + rv.w;
    *(float4*)(out + ro) = s;
}

// ---------------- attention: MFMA flash, 4 waves x 16 queries ----------------
__global__ __launch_bounds__(256) void attn_mfma_k(const bf16* __restrict__ qkv, bf16* __restrict__ o_mat) {
    int qc = blockIdx.x, head = blockIdx.y, b = blockIdx.z;
    int kvh = head >> 2;
    int tid = threadIdx.x, w = tid >> 6, l = tid & 63;
    int m16 = l & 15, h4 = l >> 4;

    __shared__ short Qs[64][64];
    __shared__ short Ks[64][64];
    __shared__ short Vt[64][64];           // [dim][key]
    __shared__ short Ps[4][16][64];        // per-wave P tile [q][key]

    const long rowq0 = (long)b * TC + MG + qc * 64;
    const bf16* kbase = qkv + ((long)b * TC) * 1536 + 1024 + kvh * DH;
    const bf16* vbase = kbase + 256;

#pragma unroll
    for (int p = 0; p < 2; ++p) {
        int rr = p * 32 + (tid >> 3);
        gl16(qkv + (rowq0 + rr) * 1536 + head * DH + (tid & 7) * 8, &Qs[rr][(tid & 7) * 8]);
    }

    float a_m[4] = {-1e30f, -1e30f, -1e30f, -1e30f};
    float a_l[4] = {0.f, 0.f, 0.f, 0.f};
    floatx4 acc_o[4];
#pragma unroll
    for (int dt = 0; dt < 4; ++dt) acc_o[dt] = (floatx4){0.f, 0.f, 0.f, 0.f};
    short8 aq[2];

    int qtok0 = MG + qc * 64 + w * 16 + h4 * 4;
    int ntiles = qc + 2;

    for (int t = 0; t < ntiles; ++t) {
        int jt = t * 64;
#pragma unroll
        for (int p = 0; p < 2; ++p) {
            int rr = p * 32 + (tid >> 3);
            int gk = min(jt + rr, TC - 1);
            gl16(kbase + (long)gk * 1536 + (tid & 7) * 8, &Ks[rr][(tid & 7) * 8]);
        }
#pragma unroll
        for (int p = 0; p < 2; ++p) {
            int cg = p * 4 + w;
            int gk = min(jt + l, TC - 1);
            short8 vv = *(const short8*)(vbase + (long)gk * 1536 + cg * 8);
#pragma unroll
            for (int e = 0; e < 8; ++e) Vt[cg * 8 + e][l] = vv[e];
        }
        __syncthreads();
        if (t == 0) {
            aq[0] = *(const short8*)&Qs[w * 16 + m16][h4 * 8];
            aq[1] = *(const short8*)&Qs[w * 16 + m16][32 + h4 * 8];
        }
        floatx4 s[4];
#pragma unroll
        for (int st = 0; st < 4; ++st) {
            s[st] = (floatx4){0.f, 0.f, 0.f, 0.f};
#pragma unroll
            for (int c = 0; c < 2; ++c) {
                short8 kf = *(const short8*)&Ks[st * 16 + m16][c * 32 + h4 * 8];
                s[st] = __builtin_amdgcn_mfma_f32_16x16x32_bf16(aq[c], kf, s[st], 0, 0, 0);
            }
        }
#pragma unroll
        for (int st = 0; st < 4; ++st) {
            int keyg = jt + st * 16 + m16;
#pragma unroll
            for (int r = 0; r < 4; ++r) {
                float v = s[st][r] * 0.125f;
                s[st][r] = (keyg > qtok0 + r) ? -1e30f : v;
            }
        }
#pragma unroll
        for (int r = 0; r < 4; ++r) {
            float tm = fmaxf(fmaxf(s[0][r], s[1][r]), fmaxf(s[2][r], s[3][r]));
            tm = fmaxf(tm, __shfl_xor(tm, 1));
            tm = fmaxf(tm, __shfl_xor(tm, 2));
            tm = fmaxf(tm, __shfl_xor(tm, 4));
            tm = fmaxf(tm, __shfl_xor(tm, 8));
            float mn = fmaxf(a_m[r], tm);
            float rs = __expf(a_m[r] - mn);
            a_m[r] = mn;
            float ps = 0.f;
#pragma unroll
            for (int st = 0; st < 4; ++st) {
                float p = __expf(s[st][r] - mn);
                s[st][r] = p;
                ps += p;
            }
            ps += __shfl_xor(ps, 1); ps += __shfl_xor(ps, 2);
            ps += __shfl_xor(ps, 4); ps += __shfl_xor(ps, 8);
            a_l[r] = a_l[r] * rs + ps;
#pragma unroll
            for (int dt = 0; dt < 4; ++dt) acc_o[dt][r] *= rs;
#pragma unroll
            for (int st = 0; st < 4; ++st) {
                bf16 hb = __float2bfloat16(s[st][r]);
                Ps[w][h4 * 4 + r][st * 16 + m16] = *reinterpret_cast<short*>(&hb);
            }
        }
#pragma unroll
        for (int c = 0; c < 2; ++c) {
            short8 ap = *(const short8*)&Ps[w][m16][c * 32 + h4 * 8];
#pragma unroll
            for (int dt = 0; dt < 4; ++dt) {
                short8 vf = *(const short8*)&Vt[dt * 16 + m16][c * 32 + h4 * 8];
                acc_o[dt] = __builtin_amdgcn_mfma_f32_16x16x32_bf16(ap, vf, acc_o[dt], 0, 0, 0);
            }
        }
        __syncthreads();
    }

#pragma unroll
    for (int r = 0; r < 4; ++r) {
        float inv = 1.f / a_l[r];
        long row = (long)b * CHUNK + qc * 64 + w * 16 + h4 * 4 + r;
#pragma unroll
        for (int dt = 0; dt < 4; ++dt)
            o_mat[row * Dm + head * DH + dt * 16 + m16] = __float2bfloat16(acc_o[dt][r] * inv);
    }
}

// mean over 256 chunk rows -> mean_c[b][d]
__global__ __launch_bounds__(256) void col_mean_k(const float* __restrict__ c, long stepOff, float* __restrict__ mean_c) {
    int b = blockIdx.y;
    int d = blockIdx.x * 256 + threadIdx.x;
    const float* base = c + (long)b * TD + stepOff + d;
    float s = 0.f;
    for (int r = 0; r < CHUNK; ++r) s += base[(long)r * Dm];
    mean_c[b * Dm + d] = s * (1.f / CHUNK);
}

// st[b][ss] = mean_c[b] . Wsp[ss] + bsp[ss]
__global__ __launch_bounds__(128) void state_update_k(const float* __restrict__ mean_c, const float* __restrict__ Wsp,
                                                      const float* __restrict__ bsp, float* __restrict__ st) {
    int b = blockIdx.x, ss = threadIdx.x;
    const float* mr = mean_c + b * Dm;
    const float* wr = Wsp + (long)ss * Dm;
    float a = bsp[ss];
#pragma unroll 4
    for (int d = 0; d < Dm; ++d) a += mr[d] * wr[d];
    st[b * SDIM + ss] = a;
}

// ---------------- orchestration ----------------

extern "C" void kernel_launch(void* const* d_in, const int* in_sizes, int n_in,
                              void* d_out, int out_size, void* d_ws, size_t ws_size,
                              hipStream_t stream) {
    const float* x     = (const float*)d_in[0];
    const float* state = (const float*)d_in[1];
    const float* Wq    = (const float*)d_in[2];
    const float* Wk    = (const float*)d_in[3];
    const float* Wv    = (const float*)d_in[4];
    const float* Wo    = (const float*)d_in[5];
    const float* bo    = (const float*)d_in[6];
    const float* lag   = (const float*)d_in[7];
    const float* lab   = (const float*)d_in[8];
    const float* lfg   = (const float*)d_in[9];
    const float* lfb   = (const float*)d_in[10];
    const float* W1    = (const float*)d_in[11];
    const float* b1    = (const float*)d_in[12];
    const float* W2    = (const float*)d_in[13];
    const float* b2    = (const float*)d_in[14];
    const float* Wsp   = (const float*)d_in[15];
    const float* bsp   = (const float*)d_in[16];
    const float* Wsi   = (const float*)d_in[17];
    const float* bsi   = (const float*)d_in[18];
    const float* gtok  = (const float*)d_in[19];

    float* out = (float*)d_out;
    char*  wsb = (char*)d_ws;

    // workspace layout (bytes); qkvb/u and o_mat/t_ln are time-aliased
    bf16* wqkv  = (bf16*)(wsb);                       // 1536x1024      (3,145,728 B)
    bf16* wo    = (bf16*)(wsb + 3145728);             // 1024x1024      (2,097,152 B)
    bf16* w1    = (bf16*)(wsb + 5242880);             // 4096x1024      (8,388,608 B)
    bf16* w2    = (bf16*)(wsb + 13631488);            // 1024x4096      (8,388,608 B)
    bf16* h_in  = (bf16*)(wsb + 22020096);            // 1152x1024 rows (2,359,296 B) [96 pad rows]
    char* scrA  = wsb + 24379392;                      // max(qkvb 3.24MB, u 8.39MB)
    bf16* qkvb  = (bf16*)scrA;                         // 1056x1536 bf16
    bf16* u     = (bf16*)scrA;                         // 1024x4096 bf16
    char* scrB  = wsb + 32768000;                      // max(o_mat, t_ln) bf16 1024x1024
    bf16* o_mat = (bf16*)scrB;
    bf16* t_ln  = (bf16*)scrB;
    float* si     = (float*)(wsb + 34865152);          // 4096 f32
    float* mean_c = (float*)(wsb + 34881536);          // 4096 f32
    float* st     = (float*)(wsb + 34897920);          // 512 f32
    float* part   = (float*)(wsb + 34901248);          // 2 x 1024x1024 f32 (8,388,608 B) -> ~43.3MB total

    // ---- setup: state copy, weight conversion, global-token rows ----
    vcopy_k<<<1, 512, 0, stream>>>(state, st, 512);
    cvt_bf16_k<<<1024, 256, 0, stream>>>(Wq, wqkv,            262144);
    cvt_bf16_k<<< 256, 256, 0, stream>>>(Wk, wqkv + 1048576,   65536);
    cvt_bf16_k<<< 256, 256, 0, stream>>>(Wv, wqkv + 1310720,   65536);
    cvt_bf16_k<<<1024, 256, 0, stream>>>(Wo, wo,              262144);
    cvt_bf16_k<<<4096, 256, 0, stream>>>(W1, w1,             1048576);
    cvt_bf16_k<<<4096, 256, 0, stream>>>(W2, w2,             1048576);
    fill_globals_k<<<128, 256, 0, stream>>>(gtok, h_in);

    for (int s = 0; s < NSTEP; ++s) {
        long roff = (long)s * CHUNK;
        state_proj_k<<<16, 256, 0, stream>>>(st, Wsi, bsi, si);
        // attn LN -> h_in rows MG..263 (bf16)
        ln_rows_k<<<dim3(256, 4), 256, 0, stream>>>(x, TD, roff, h_in, (long)TC * Dm, MG, lag, lab, si);
        // QKV: [1056 x 1536 x 1024] -> qkvb bf16 contiguous
        gemm_bf16<<<dim3(12, 9, 1), 256, 0, stream>>>(
            h_in, wqkv, Bn * TC, 1536, 1024, 1024,
            qkvb, 1536, nullptr, 0, nullptr, 0L);
        attn_mfma_k<<<dim3(4, 16, 4), 256, 0, stream>>>(qkvb, o_mat);
        // Wo split-K (KS=2) -> part, then reduce(+bo, +x) -> out (c_pre)
        gemm_bf16<<<dim3(8, 8, 2), 256, 0, stream>>>(
            o_mat, wo, Bn * CHUNK, 1024, 1024, 512,
            nullptr, 0, nullptr, 0, part, 1048576L);
        reduce_splitk_k<<<1024, 256, 0, stream>>>(part, 2, bo, x, out, roff);
        // ffn LN -> t_ln bf16
        ln_rows_k<<<dim3(256, 4), 256, 0, stream>>>(out, TD, roff, t_ln, (long)CHUNK * Dm, 0, lfg, lfb, nullptr);
        // FFN1 + gelu -> u bf16
        gemm_bf16<<<dim3(32, 8, 1), 256, 0, stream>>>(
            t_ln, w1, Bn * CHUNK, 4096, 1024, 1024,
            u, 4096, b1, 1, nullptr, 0L);
        // FFN2 split-K (KS=2) -> part, then reduce(+b2, +c_pre) -> out (final c)
        gemm_bf16<<<dim3(8, 8, 2), 256, 0, stream>>>(
            u, w2, Bn * CHUNK, 1024, 4096, 2048,
            nullptr, 0, nullptr, 0, part, 1048576L);
        reduce_splitk_k<<<1024, 256, 0, stream>>>(part, 2, b2, out, out, roff);
        // state update
        col_mean_k<<<dim3(4, 4), 256, 0, stream>>>(out, roff * Dm, mean_c);
        state_update_k<<<4, 128, 0, stream>>>(mean_c, Wsp, bsp, st);
    }
    vcopy_k<<<1, 512, 0, stream>>>(st, out + (long)Bn * Tn * Dm, 512);
}

// Round 5
// 2525.967 us; speedup vs baseline: 4.4553x; 1.3015x over previous
//
#include <hip/hip_runtime.h>
#include <hip/hip_bf16.h>

// Sizes
#define Dm    1024
#define Hn    16
#define KVH   4
#define DH    64
#define CHUNK 256
#define SDIM  128
#define MG    8
#define Bn    4
#define Tn    4096
#define TC    264            // MG + CHUNK
#define NSTEP 16
#define TD    4194304L       // Tn*Dm per batch

typedef __attribute__((ext_vector_type(8))) short short8;
typedef __attribute__((ext_vector_type(4))) float floatx4;
typedef __hip_bfloat16 bf16;

__device__ __forceinline__ void gl16(const void* g, void* l) {
    using GP = const __attribute__((address_space(1))) char*;
    using LP = __attribute__((address_space(3))) char*;
    __builtin_amdgcn_global_load_lds((GP)g, (LP)l, 16, 0, 0);
}

// ---------------- utility kernels ----------------

__global__ __launch_bounds__(512) void vcopy_k(const float* __restrict__ s, float* __restrict__ d, int n) {
    int i = blockIdx.x * 512 + threadIdx.x;
    if (i < n) d[i] = s[i];
}

__global__ __launch_bounds__(256) void cvt_bf16_k(const float* __restrict__ s, bf16* __restrict__ d, int n4) {
    int i = blockIdx.x * 256 + threadIdx.x;
    if (i >= n4) return;
    float4 v = ((const float4*)s)[i];
    bf16* o = d + i * 4;
    o[0] = __float2bfloat16(v.x); o[1] = __float2bfloat16(v.y);
    o[2] = __float2bfloat16(v.z); o[3] = __float2bfloat16(v.w);
}

__global__ __launch_bounds__(256) void fill_globals_k(const float* __restrict__ gtok, bf16* __restrict__ h_in) {
    int idx = blockIdx.x * 256 + threadIdx.x;      // 0..32767  (4 b * 8 rows * 1024)
    int b = idx >> 13, rd = idx & 8191;
    h_in[(long)b * (TC * Dm) + rd] = __float2bfloat16(gtok[rd]);
}

// si[b][d] = st[b] . Wsi[d] + bsi[d]; grid (4, 16) x 64 threads (1 wave)
__global__ __launch_bounds__(64) void state_proj_k(const float* __restrict__ st, const float* __restrict__ Wsi,
                                                   const float* __restrict__ bsi, float* __restrict__ si) {
    int b = blockIdx.x, g = blockIdx.y;
    int d = g * 64 + threadIdx.x;
    const float* sr = st + b * SDIM;
    const float* wr = Wsi + (long)d * SDIM;
    float a = bsi[d];
#pragma unroll
    for (int k4 = 0; k4 < 32; ++k4) {
        float4 sv = *(const float4*)(sr + k4 * 4);
        float4 wv = *(const float4*)(wr + k4 * 4);
        a += sv.x * wv.x + sv.y * wv.y + sv.z * wv.z + sv.w * wv.w;
    }
    si[b * Dm + d] = a;
}

// LayerNorm of one 1024-row per block; optional per-batch add vector (si). bf16 output.
__global__ __launch_bounds__(256) void ln_rows_k(const float* __restrict__ in, long inS, long inRoff,
                                                 bf16* __restrict__ out, long outS, long outRoff,
                                                 const float* __restrict__ g, const float* __restrict__ be,
                                                 const float* __restrict__ add) {
    int r = blockIdx.x, b = blockIdx.y, tid = threadIdx.x;
    const float* row = in + (long)b * inS + (inRoff + r) * (long)Dm;
    float4 v = *(const float4*)(row + tid * 4);
    float s = v.x + v.y + v.z + v.w;
    float q = v.x * v.x + v.y * v.y + v.z * v.z + v.w * v.w;
    for (int off = 32; off > 0; off >>= 1) { s += __shfl_down(s, off); q += __shfl_down(q, off); }
    __shared__ float red[10];
    int w = tid >> 6;
    if ((tid & 63) == 0) { red[w] = s; red[4 + w] = q; }
    __syncthreads();
    if (tid == 0) {
        float ts = red[0] + red[1] + red[2] + red[3];
        float tq = red[4] + red[5] + red[6] + red[7];
        float mean = ts * (1.f / Dm);
        float var = tq * (1.f / Dm) - mean * mean;
        red[8] = mean;
        red[9] = rsqrtf(var + 1e-5f);
    }
    __syncthreads();
    float mean = red[8], rstd = red[9];
    int d = tid * 4;
    float4 gv = *(const float4*)(g + d);
    float4 bv = *(const float4*)(be + d);
    float o0 = (v.x - mean) * rstd * gv.x + bv.x;
    float o1 = (v.y - mean) * rstd * gv.y + bv.y;
    float o2 = (v.z - mean) * rstd * gv.z + bv.z;
    float o3 = (v.w - mean) * rstd * gv.w + bv.w;
    if (add) {
        float4 av = *(const float4*)(add + b * Dm + d);
        o0 += av.x; o1 += av.y; o2 += av.z; o3 += av.w;
    }
    bf16* orow = out + (long)b * outS + (outRoff + r) * (long)Dm + d;
    orow[0] = __float2bfloat16(o0); orow[1] = __float2bfloat16(o1);
    orow[2] = __float2bfloat16(o2); orow[3] = __float2bfloat16(o3);
}

// ---------------- bf16 MFMA GEMM, depth-3 pipelined (4 LDS buffers), optional split-K ----------------
// A: [Mpad][K] bf16 row-major. W: [N][K] bf16 row-major. K-range per block-z:
// [z*kspan, (z+1)*kspan). If Cpart: raw f32 partial to Cpart + z*partMN + m*N + n.
// Else: bf16 out Cb[m*ldc+n] (+bias, optional exact GELU).
__global__ __launch_bounds__(256) void gemm_bf16(
    const bf16* __restrict__ A, const bf16* __restrict__ W,
    int M, int N, int K, int kspan,
    bf16* __restrict__ Cb, int ldc, const float* __restrict__ bias, int gelu,
    float* __restrict__ Cpart, long partMN)
{
    __shared__ short As[4][4096];
    __shared__ short Bs[4][4096];
    int tid = threadIdx.x;
    int w = tid >> 6, l = tid & 63;
    int wr = w >> 1, wc = w & 1;
    int m0 = blockIdx.y << 7, n0 = blockIdx.x << 7;
    int kb = blockIdx.z * kspan;

    int r0 = w * 16 + (l >> 2);          // staged row for this lane (seg w)
    int kc = (l & 3) << 3;               // k elem offset (8 bf16 = 16B)
    const bf16* pA0 = A + (long)(m0 + r0) * K + kc + kb;
    const bf16* pA1 = pA0 + (long)64 * K;
    const bf16* pW0 = W + (long)(n0 + r0) * K + kc + kb;
    const bf16* pW1 = pW0 + (long)64 * K;
    int lofs = w * 1024 + l * 16;        // byte offset of this lane's 16B slot
    char* cA = (char*)As;
    char* cB = (char*)Bs;

    floatx4 acc[4][4];
#pragma unroll
    for (int i = 0; i < 4; ++i)
#pragma unroll
        for (int j = 0; j < 4; ++j) acc[i][j] = (floatx4){0.f, 0.f, 0.f, 0.f};

    int arow = wr * 64 + (l & 15);
    int brow = wc * 64 + (l & 15);
    int acol = (l >> 4) << 3;

    int nk = kspan >> 5;

#define STAGE(t)                                            \
    {                                                       \
        int kt_ = (t) << 5;                                 \
        int bo_ = ((t) & 3) * 8192;                         \
        gl16(pA0 + kt_, cA + bo_ + lofs);                   \
        gl16(pA1 + kt_, cA + bo_ + 4096 + lofs);            \
        gl16(pW0 + kt_, cB + bo_ + lofs);                   \
        gl16(pW1 + kt_, cB + bo_ + 4096 + lofs);            \
    }

    int issued = 0;
    for (; issued < 3 && issued < nk; ++issued) STAGE(issued);

    for (int i = 0; i < nk; ++i) {
        if (issued < nk) { STAGE(issued); ++issued; }
        int pend = issued - i - 1;       // tiles beyond i still in flight
        switch (pend) {
            case 3: asm volatile("s_waitcnt vmcnt(12)" ::: "memory"); break;
            case 2: asm volatile("s_waitcnt vmcnt(8)" ::: "memory"); break;
            case 1: asm volatile("s_waitcnt vmcnt(4)" ::: "memory"); break;
            default: asm volatile("s_waitcnt vmcnt(0)" ::: "memory"); break;
        }
        __builtin_amdgcn_s_barrier();    // all waves' tile-i loads in LDS
        __builtin_amdgcn_sched_barrier(0);
        const short* Ab = As[i & 3];
        const short* Bb = Bs[i & 3];
        short8 a[4], b[4];
#pragma unroll
        for (int t = 0; t < 4; ++t) {
            a[t] = *(const short8*)&Ab[(arow + t * 16) * 32 + acol];
            b[t] = *(const short8*)&Bb[(brow + t * 16) * 32 + acol];
        }
#pragma unroll
        for (int ii = 0; ii < 4; ++ii)
#pragma unroll
            for (int jj = 0; jj < 4; ++jj)
                acc[ii][jj] = __builtin_amdgcn_mfma_f32_16x16x32_bf16(a[ii], b[jj], acc[ii][jj], 0, 0, 0);
        __builtin_amdgcn_sched_barrier(0);
        __builtin_amdgcn_s_barrier();    // reads of tile i done before its buffer is re-staged
    }
#undef STAGE

    // epilogue: D row = m0 + wr*64 + i*16 + (l>>4)*4 + rr ; col = n0 + wc*64 + j*16 + (l&15)
    int crow0 = m0 + wr * 64 + ((l >> 4) << 2);
    int ccol0 = n0 + wc * 64 + (l & 15);
    if (Cpart) {
        float* pp = Cpart + (long)blockIdx.z * partMN;
#pragma unroll
        for (int i = 0; i < 4; ++i)
#pragma unroll
            for (int rr = 0; rr < 4; ++rr) {
                int m = crow0 + i * 16 + rr;
                if (m >= M) continue;
#pragma unroll
                for (int j = 0; j < 4; ++j)
                    pp[(long)m * N + ccol0 + j * 16] = acc[i][j][rr];
            }
    } else {
#pragma unroll
        for (int i = 0; i < 4; ++i)
#pragma unroll
            for (int rr = 0; rr < 4; ++rr) {
                int m = crow0 + i * 16 + rr;
                if (m >= M) continue;
                bf16* crow = Cb + (long)m * ldc;
#pragma unroll
                for (int j = 0; j < 4; ++j) {
                    int n = ccol0 + j * 16;
                    float v = acc[i][j][rr];
                    if (bias) v += bias[n];
                    if (gelu) v = 0.5f * v * (1.f + erff(v * 0.70710678118654752f));
                    crow[n] = __float2bfloat16(v);
                }
            }
    }
}

// ---------------- split-K reduce: out[map(m,n)] = sum_z part[z] + bias + res ----------------
__global__ __launch_bounds__(256) void reduce_splitk_k(const float* __restrict__ part, int KS,
                                                       const float* __restrict__ bias,
                                                       const float* __restrict__ res,
                                                       float* __restrict__ out, long roff) {
    int e4 = blockIdx.x * 256 + threadIdx.x;        // 0..262143 (float4 elements)
    int m = e4 >> 8, n4 = e4 & 255;
    float4 s = ((const float4*)part)[e4];
    for (int z = 1; z < KS; ++z) {
        float4 p = ((const float4*)(part + (long)z * 1048576))[e4];
        s.x += p.x; s.y += p.y; s.z += p.z; s.w += p.w;
    }
    float4 bv = ((const float4*)bias)[n4];
    long ro = (long)(m >> 8) * TD + (roff + (m & 255)) * 1024L + n4 * 4;
    float4 rv = *(const float4*)(res + ro);
    s.x += bv.x + rv.x; s.y += bv.y + rv.y; s.z += bv.z + rv.z; s.w += bv.w + rv.w;
    *(float4*)(out + ro) = s;
}

// ---------------- attention: MFMA flash, 4 waves x 16 queries ----------------
__global__ __launch_bounds__(256) void attn_mfma_k(const bf16* __restrict__ qkv, bf16* __restrict__ o_mat) {
    int qc = blockIdx.x, head = blockIdx.y, b = blockIdx.z;
    int kvh = head >> 2;
    int tid = threadIdx.x, w = tid >> 6, l = tid & 63;
    int m16 = l & 15, h4 = l >> 4;

    __shared__ short Qs[64][64];
    __shared__ short Ks[64][64];
    __shared__ short Vt[64][64];           // [dim][key]
    __shared__ short Ps[4][16][64];        // per-wave P tile [q][key]

    const long rowq0 = (long)b * TC + MG + qc * 64;
    const bf16* kbase = qkv + ((long)b * TC) * 1536 + 1024 + kvh * DH;
    const bf16* vbase = kbase + 256;

#pragma unroll
    for (int p = 0; p < 2; ++p) {
        int rr = p * 32 + (tid >> 3);
        gl16(qkv + (rowq0 + rr) * 1536 + head * DH + (tid & 7) * 8, &Qs[rr][(tid & 7) * 8]);
    }

    float a_m[4] = {-1e30f, -1e30f, -1e30f, -1e30f};
    float a_l[4] = {0.f, 0.f, 0.f, 0.f};
    floatx4 acc_o[4];
#pragma unroll
    for (int dt = 0; dt < 4; ++dt) acc_o[dt] = (floatx4){0.f, 0.f, 0.f, 0.f};
    short8 aq[2];

    int qtok0 = MG + qc * 64 + w * 16 + h4 * 4;
    int ntiles = qc + 2;

    for (int t = 0; t < ntiles; ++t) {
        int jt = t * 64;
#pragma unroll
        for (int p = 0; p < 2; ++p) {
            int rr = p * 32 + (tid >> 3);
            int gk = min(jt + rr, TC - 1);
            gl16(kbase + (long)gk * 1536 + (tid & 7) * 8, &Ks[rr][(tid & 7) * 8]);
        }
#pragma unroll
        for (int p = 0; p < 2; ++p) {
            int cg = p * 4 + w;
            int gk = min(jt + l, TC - 1);
            short8 vv = *(const short8*)(vbase + (long)gk * 1536 + cg * 8);
#pragma unroll
            for (int e = 0; e < 8; ++e) Vt[cg * 8 + e][l] = vv[e];
        }
        __syncthreads();
        if (t == 0) {
            aq[0] = *(const short8*)&Qs[w * 16 + m16][h4 * 8];
            aq[1] = *(const short8*)&Qs[w * 16 + m16][32 + h4 * 8];
        }
        floatx4 s[4];
#pragma unroll
        for (int st = 0; st < 4; ++st) {
            s[st] = (floatx4){0.f, 0.f, 0.f, 0.f};
#pragma unroll
            for (int c = 0; c < 2; ++c) {
                short8 kf = *(const short8*)&Ks[st * 16 + m16][c * 32 + h4 * 8];
                s[st] = __builtin_amdgcn_mfma_f32_16x16x32_bf16(aq[c], kf, s[st], 0, 0, 0);
            }
        }
#pragma unroll
        for (int st = 0; st < 4; ++st) {
            int keyg = jt + st * 16 + m16;
#pragma unroll
            for (int r = 0; r < 4; ++r) {
                float v = s[st][r] * 0.125f;
                s[st][r] = (keyg > qtok0 + r) ? -1e30f : v;
            }
        }
#pragma unroll
        for (int r = 0; r < 4; ++r) {
            float tm = fmaxf(fmaxf(s[0][r], s[1][r]), fmaxf(s[2][r], s[3][r]));
            tm = fmaxf(tm, __shfl_xor(tm, 1));
            tm = fmaxf(tm, __shfl_xor(tm, 2));
            tm = fmaxf(tm, __shfl_xor(tm, 4));
            tm = fmaxf(tm, __shfl_xor(tm, 8));
            float mn = fmaxf(a_m[r], tm);
            float rs = __expf(a_m[r] - mn);
            a_m[r] = mn;
            float ps = 0.f;
#pragma unroll
            for (int st = 0; st < 4; ++st) {
                float p = __expf(s[st][r] - mn);
                s[st][r] = p;
                ps += p;
            }
            ps += __shfl_xor(ps, 1); ps += __shfl_xor(ps, 2);
            ps += __shfl_xor(ps, 4); ps += __shfl_xor(ps, 8);
            a_l[r] = a_l[r] * rs + ps;
#pragma unroll
            for (int dt = 0; dt < 4; ++dt) acc_o[dt][r] *= rs;
#pragma unroll
            for (int st = 0; st < 4; ++st) {
                bf16 hb = __float2bfloat16(s[st][r]);
                Ps[w][h4 * 4 + r][st * 16 + m16] = *reinterpret_cast<short*>(&hb);
            }
        }
#pragma unroll
        for (int c = 0; c < 2; ++c) {
            short8 ap = *(const short8*)&Ps[w][m16][c * 32 + h4 * 8];
#pragma unroll
            for (int dt = 0; dt < 4; ++dt) {
                short8 vf = *(const short8*)&Vt[dt * 16 + m16][c * 32 + h4 * 8];
                acc_o[dt] = __builtin_amdgcn_mfma_f32_16x16x32_bf16(ap, vf, acc_o[dt], 0, 0, 0);
            }
        }
        __syncthreads();
    }

#pragma unroll
    for (int r = 0; r < 4; ++r) {
        float inv = 1.f / a_l[r];
        long row = (long)b * CHUNK + qc * 64 + w * 16 + h4 * 4 + r;
#pragma unroll
        for (int dt = 0; dt < 4; ++dt)
            o_mat[row * Dm + head * DH + dt * 16 + m16] = __float2bfloat16(acc_o[dt][r] * inv);
    }
}

// ---------------- column-sum partials: grid (b=4, rg=8), 256 thr; 32 rows per block ----------------
__global__ __launch_bounds__(256) void col_part_k(const float* __restrict__ c, long stepOff,
                                                  float* __restrict__ colp) {
    int b = blockIdx.x, rg = blockIdx.y;
    int d4 = threadIdx.x;                 // dims d4*4 .. d4*4+3
    const float* base = c + (long)b * TD + stepOff + (long)(rg * 32) * Dm + d4 * 4;
    float4 s = make_float4(0.f, 0.f, 0.f, 0.f);
    for (int r = 0; r < 32; ++r) {
        float4 v = *(const float4*)(base + (long)r * Dm);
        s.x += v.x; s.y += v.y; s.z += v.z; s.w += v.w;
    }
    *(float4*)(colp + ((b * 8 + rg) << 10) + d4 * 4) = s;
}

// ---------------- state update: grid (4, 32) x 256 thr; wave per ss output ----------------
__global__ __launch_bounds__(256) void state_update_k(const float* __restrict__ colp,
                                                      const float* __restrict__ Wsp,
                                                      const float* __restrict__ bsp,
                                                      float* __restrict__ st) {
    int b = blockIdx.x;
    int tid = threadIdx.x, w = tid >> 6, l = tid & 63;
    int ss = blockIdx.y * 4 + w;
    float4 m[4];
#pragma unroll
    for (int t = 0; t < 4; ++t) m[t] = make_float4(0.f, 0.f, 0.f, 0.f);
    for (int rg = 0; rg < 8; ++rg) {
        const float* pr = colp + ((b * 8 + rg) << 10) + l * 16;
#pragma unroll
        for (int t = 0; t < 4; ++t) {
            float4 v = *(const float4*)(pr + t * 4);
            m[t].x += v.x; m[t].y += v.y; m[t].z += v.z; m[t].w += v.w;
        }
    }
    const float* wr = Wsp + (long)ss * Dm + l * 16;
    float a = 0.f;
#pragma unroll
    for (int t = 0; t < 4; ++t) {
        float4 wv = *(const float4*)(wr + t * 4);
        a += m[t].x * wv.x + m[t].y * wv.y + m[t].z * wv.z + m[t].w * wv.w;
    }
    a *= (1.f / CHUNK);
    for (int off = 32; off > 0; off >>= 1) a += __shfl_down(a, off);
    if (l == 0) st[b * SDIM + ss] = a + bsp[ss];
}

// ---------------- orchestration ----------------

extern "C" void kernel_launch(void* const* d_in, const int* in_sizes, int n_in,
                              void* d_out, int out_size, void* d_ws, size_t ws_size,
                              hipStream_t stream) {
    const float* x     = (const float*)d_in[0];
    const float* state = (const float*)d_in[1];
    const float* Wq    = (const float*)d_in[2];
    const float* Wk    = (const float*)d_in[3];
    const float* Wv    = (const float*)d_in[4];
    const float* Wo    = (const float*)d_in[5];
    const float* bo    = (const float*)d_in[6];
    const float* lag   = (const float*)d_in[7];
    const float* lab   = (const float*)d_in[8];
    const float* lfg   = (const float*)d_in[9];
    const float* lfb   = (const float*)d_in[10];
    const float* W1    = (const float*)d_in[11];
    const float* b1    = (const float*)d_in[12];
    const float* W2    = (const float*)d_in[13];
    const float* b2    = (const float*)d_in[14];
    const float* Wsp   = (const float*)d_in[15];
    const float* bsp   = (const float*)d_in[16];
    const float* Wsi   = (const float*)d_in[17];
    const float* bsi   = (const float*)d_in[18];
    const float* gtok  = (const float*)d_in[19];

    float* out = (float*)d_out;
    char*  wsb = (char*)d_ws;

    // workspace layout (bytes); qkvb/u and o_mat/t_ln/colp are time-aliased
    bf16* wqkv  = (bf16*)(wsb);                       // 1536x1024      (3,145,728 B)
    bf16* wo    = (bf16*)(wsb + 3145728);             // 1024x1024      (2,097,152 B)
    bf16* w1    = (bf16*)(wsb + 5242880);             // 4096x1024      (8,388,608 B)
    bf16* w2    = (bf16*)(wsb + 13631488);            // 1024x4096      (8,388,608 B)
    bf16* h_in  = (bf16*)(wsb + 22020096);            // 1152x1024 rows (2,359,296 B) [96 pad rows]
    char* scrA  = wsb + 24379392;                      // max(qkvb 3.24MB, u 8.39MB)
    bf16* qkvb  = (bf16*)scrA;
    bf16* u     = (bf16*)scrA;
    char* scrB  = wsb + 32768000;                      // o_mat / t_ln / colp (time-aliased, 2MB)
    bf16* o_mat = (bf16*)scrB;
    bf16* t_ln  = (bf16*)scrB;
    float* colp = (float*)scrB;                        // 4*8*1024 f32 = 128KB
    float* si     = (float*)(wsb + 34865152);          // 4096 f32
    float* st     = (float*)(wsb + 34897920);          // 512 f32
    float* part   = (float*)(wsb + 34901248);          // 2 x 1024x1024 f32 (8,388,608 B)

    // ---- setup: state copy, weight conversion, global-token rows ----
    vcopy_k<<<1, 512, 0, stream>>>(state, st, 512);
    cvt_bf16_k<<<1024, 256, 0, stream>>>(Wq, wqkv,            262144);
    cvt_bf16_k<<< 256, 256, 0, stream>>>(Wk, wqkv + 1048576,   65536);
    cvt_bf16_k<<< 256, 256, 0, stream>>>(Wv, wqkv + 1310720,   65536);
    cvt_bf16_k<<<1024, 256, 0, stream>>>(Wo, wo,              262144);
    cvt_bf16_k<<<4096, 256, 0, stream>>>(W1, w1,             1048576);
    cvt_bf16_k<<<4096, 256, 0, stream>>>(W2, w2,             1048576);
    fill_globals_k<<<128, 256, 0, stream>>>(gtok, h_in);

    for (int s = 0; s < NSTEP; ++s) {
        long roff = (long)s * CHUNK;
        state_proj_k<<<dim3(4, 16), 64, 0, stream>>>(st, Wsi, bsi, si);
        // attn LN -> h_in rows MG..263 (bf16)
        ln_rows_k<<<dim3(256, 4), 256, 0, stream>>>(x, TD, roff, h_in, (long)TC * Dm, MG, lag, lab, si);
        // QKV: [1056 x 1536 x 1024] -> qkvb bf16 contiguous
        gemm_bf16<<<dim3(12, 9, 1), 256, 0, stream>>>(
            h_in, wqkv, Bn * TC, 1536, 1024, 1024,
            qkvb, 1536, nullptr, 0, nullptr, 0L);
        attn_mfma_k<<<dim3(4, 16, 4), 256, 0, stream>>>(qkvb, o_mat);
        // Wo split-K (KS=2) -> part, then reduce(+bo, +x) -> out (c_pre)
        gemm_bf16<<<dim3(8, 8, 2), 256, 0, stream>>>(
            o_mat, wo, Bn * CHUNK, 1024, 1024, 512,
            nullptr, 0, nullptr, 0, part, 1048576L);
        reduce_splitk_k<<<1024, 256, 0, stream>>>(part, 2, bo, x, out, roff);
        // ffn LN -> t_ln bf16
        ln_rows_k<<<dim3(256, 4), 256, 0, stream>>>(out, TD, roff, t_ln, (long)CHUNK * Dm, 0, lfg, lfb, nullptr);
        // FFN1 + gelu -> u bf16
        gemm_bf16<<<dim3(32, 8, 1), 256, 0, stream>>>(
            t_ln, w1, Bn * CHUNK, 4096, 1024, 1024,
            u, 4096, b1, 1, nullptr, 0L);
        // FFN2 split-K (KS=2) -> part, then reduce(+b2, +c_pre) -> out (final c)
        gemm_bf16<<<dim3(8, 8, 2), 256, 0, stream>>>(
            u, w2, Bn * CHUNK, 1024, 4096, 2048,
            nullptr, 0, nullptr, 0, part, 1048576L);
        reduce_splitk_k<<<1024, 256, 0, stream>>>(part, 2, b2, out, out, roff);
        // state update (column partials then wave-parallel dot)
        col_part_k<<<dim3(4, 8), 256, 0, stream>>>(out, roff * Dm, colp);
        state_update_k<<<dim3(4, 32), 256, 0, stream>>>(colp, Wsp, bsp, st);
    }
    vcopy_k<<<1, 512, 0, stream>>>(st, out + (long)Bn * Tn * Dm, 512);
}

// Round 6
// 1711.174 us; speedup vs baseline: 6.5767x; 1.4762x over previous
//
#include <hip/hip_runtime.h>
#include <hip/hip_bf16.h>

// Sizes
#define Dm    1024
#define Hn    16
#define KVH   4
#define DH    64
#define CHUNK 256
#define SDIM  128
#define MG    8
#define Bn    4
#define Tn    4096
#define TC    264            // MG + CHUNK
#define NSTEP 16
#define TD    4194304L       // Tn*Dm per batch

typedef __attribute__((ext_vector_type(8))) short short8;
typedef __attribute__((ext_vector_type(4))) float floatx4;
typedef __hip_bfloat16 bf16;

__device__ __forceinline__ void gl16(const void* g, void* l) {
    using GP = const __attribute__((address_space(1))) char*;
    using LP = __attribute__((address_space(3))) char*;
    __builtin_amdgcn_global_load_lds((GP)g, (LP)l, 16, 0, 0);
}

// ---------------- utility kernels ----------------

__global__ __launch_bounds__(512) void vcopy_k(const float* __restrict__ s, float* __restrict__ d, int n) {
    int i = blockIdx.x * 512 + threadIdx.x;
    if (i < n) d[i] = s[i];
}

__global__ __launch_bounds__(256) void cvt_bf16_k(const float* __restrict__ s, bf16* __restrict__ d, int n4) {
    int i = blockIdx.x * 256 + threadIdx.x;
    if (i >= n4) return;
    float4 v = ((const float4*)s)[i];
    bf16* o = d + i * 4;
    o[0] = __float2bfloat16(v.x); o[1] = __float2bfloat16(v.y);
    o[2] = __float2bfloat16(v.z); o[3] = __float2bfloat16(v.w);
}

__global__ __launch_bounds__(256) void fill_globals_k(const float* __restrict__ gtok, bf16* __restrict__ h_in) {
    int idx = blockIdx.x * 256 + threadIdx.x;      // 0..32767  (4 b * 8 rows * 1024)
    int b = idx >> 13, rd = idx & 8191;
    h_in[(long)b * (TC * Dm) + rd] = __float2bfloat16(gtok[rd]);
}

// si[b][d] = st[b] . Wsi[d] + bsi[d]; grid (4, 16) x 64 threads (1 wave)
__global__ __launch_bounds__(64) void state_proj_k(const float* __restrict__ st, const float* __restrict__ Wsi,
                                                   const float* __restrict__ bsi, float* __restrict__ si) {
    int b = blockIdx.x, g = blockIdx.y;
    int d = g * 64 + threadIdx.x;
    const float* sr = st + b * SDIM;
    const float* wr = Wsi + (long)d * SDIM;
    float a = bsi[d];
#pragma unroll
    for (int k4 = 0; k4 < 32; ++k4) {
        float4 sv = *(const float4*)(sr + k4 * 4);
        float4 wv = *(const float4*)(wr + k4 * 4);
        a += sv.x * wv.x + sv.y * wv.y + sv.z * wv.z + sv.w * wv.w;
    }
    si[b * Dm + d] = a;
}

// LayerNorm of one 1024-row per block; optional per-batch add vector (si). bf16 output.
__global__ __launch_bounds__(256) void ln_rows_k(const float* __restrict__ in, long inS, long inRoff,
                                                 bf16* __restrict__ out, long outS, long outRoff,
                                                 const float* __restrict__ g, const float* __restrict__ be,
                                                 const float* __restrict__ add) {
    int r = blockIdx.x, b = blockIdx.y, tid = threadIdx.x;
    const float* row = in + (long)b * inS + (inRoff + r) * (long)Dm;
    float4 v = *(const float4*)(row + tid * 4);
    float s = v.x + v.y + v.z + v.w;
    float q = v.x * v.x + v.y * v.y + v.z * v.z + v.w * v.w;
    for (int off = 32; off > 0; off >>= 1) { s += __shfl_down(s, off); q += __shfl_down(q, off); }
    __shared__ float red[10];
    int w = tid >> 6;
    if ((tid & 63) == 0) { red[w] = s; red[4 + w] = q; }
    __syncthreads();
    if (tid == 0) {
        float ts = red[0] + red[1] + red[2] + red[3];
        float tq = red[4] + red[5] + red[6] + red[7];
        float mean = ts * (1.f / Dm);
        float var = tq * (1.f / Dm) - mean * mean;
        red[8] = mean;
        red[9] = rsqrtf(var + 1e-5f);
    }
    __syncthreads();
    float mean = red[8], rstd = red[9];
    int d = tid * 4;
    float4 gv = *(const float4*)(g + d);
    float4 bv = *(const float4*)(be + d);
    float o0 = (v.x - mean) * rstd * gv.x + bv.x;
    float o1 = (v.y - mean) * rstd * gv.y + bv.y;
    float o2 = (v.z - mean) * rstd * gv.z + bv.z;
    float o3 = (v.w - mean) * rstd * gv.w + bv.w;
    if (add) {
        float4 av = *(const float4*)(add + b * Dm + d);
        o0 += av.x; o1 += av.y; o2 += av.z; o3 += av.w;
    }
    bf16* orow = out + (long)b * outS + (outRoff + r) * (long)Dm + d;
    orow[0] = __float2bfloat16(o0); orow[1] = __float2bfloat16(o1);
    orow[2] = __float2bfloat16(o2); orow[3] = __float2bfloat16(o3);
}

// ---------------- bf16 MFMA GEMM, 64xBN tile, 2-stage pipelined, optional split-K ----------------
// A: [Mpad][K] bf16 row-major. W: [N][K] bf16 row-major. 4 waves: each computes all 64 M-rows
// x BN/4 N-cols. K-range per block-z: [z*kspan, (z+1)*kspan).
// If Cpart: f32 partial at Cpart + z*partMN + m*N + n. Else bf16 Cb[m*ldc+n] (+bias, opt GELU).
template<int BN>
__global__ __launch_bounds__(256) void gemm64(
    const bf16* __restrict__ A, const bf16* __restrict__ W,
    int M, int N, int K, int kspan,
    bf16* __restrict__ Cb, int ldc, const float* __restrict__ bias, int gelu,
    float* __restrict__ Cpart, long partMN)
{
    constexpr int NSEG = 4 + BN / 16;     // 1KB segments per K-step (A: 4, B: BN/16)
    constexpr int SEGW = NSEG / 4;        // segments per wave
    constexpr int FC   = BN / 64;         // B-fragment columns per wave
    constexpr int WN   = BN / 4;          // N-cols per wave
    __shared__ short S[2 * NSEG * 512];

    int tid = threadIdx.x;
    int w = tid >> 6, l = tid & 63;
    int m0 = blockIdx.y << 6, n0 = blockIdx.x * BN;
    int kb = blockIdx.z * kspan;

    // staging descriptors: wave w owns segs {w, w+4, ...}; seg s<4 -> A rows s*16..;
    // seg s>=4 -> B rows (s-4)*16..  Lane l covers row base+(l>>2), k-col (l&3)*8.
    const bf16* gp[SEGW];
    int so[SEGW];
#pragma unroll
    for (int si = 0; si < SEGW; ++si) {
        int s = w + si * 4;
        const bf16* base = (s < 4) ? (A + (long)(m0 + s * 16 + (l >> 2)) * K)
                                   : (W + (long)(n0 + (s - 4) * 16 + (l >> 2)) * K);
        gp[si] = base + ((l & 3) << 3) + kb;
        so[si] = s * 1024 + l * 16;
    }
    char* cS = (char*)S;
    constexpr int LDSB = NSEG * 1024;     // bytes per buffer

    floatx4 acc[4][FC];
#pragma unroll
    for (int t = 0; t < 4; ++t)
#pragma unroll
        for (int u = 0; u < FC; ++u) acc[t][u] = (floatx4){0.f, 0.f, 0.f, 0.f};

    int arow = l & 15;
    int acol = (l >> 4) << 3;
    int nk = kspan >> 5;

#define STAGE(t)                                                     \
    {                                                                \
        int kt_ = (t) << 5;                                          \
        char* b_ = cS + (((t) & 1) ? LDSB : 0);                      \
        _Pragma("unroll")                                            \
        for (int si = 0; si < SEGW; ++si) gl16(gp[si] + kt_, b_ + so[si]); \
    }

    STAGE(0)
    for (int i = 0; i < nk; ++i) {
        if (i + 1 < nk) {
            STAGE(i + 1)
            if constexpr (SEGW == 2) asm volatile("s_waitcnt vmcnt(2)" ::: "memory");
            else                     asm volatile("s_waitcnt vmcnt(3)" ::: "memory");
        } else {
            asm volatile("s_waitcnt vmcnt(0)" ::: "memory");
        }
        __builtin_amdgcn_s_barrier();
        __builtin_amdgcn_sched_barrier(0);
        const short* buf = S + (i & 1) * (NSEG * 512);
        short8 a[4], b[FC];
#pragma unroll
        for (int t = 0; t < 4; ++t)
            a[t] = *(const short8*)&buf[(t * 16 + arow) * 32 + acol];
#pragma unroll
        for (int u = 0; u < FC; ++u)
            b[u] = *(const short8*)&buf[2048 + (w * WN + u * 16 + arow) * 32 + acol];
#pragma unroll
        for (int t = 0; t < 4; ++t)
#pragma unroll
            for (int u = 0; u < FC; ++u)
                acc[t][u] = __builtin_amdgcn_mfma_f32_16x16x32_bf16(a[t], b[u], acc[t][u], 0, 0, 0);
        __builtin_amdgcn_sched_barrier(0);
        __builtin_amdgcn_s_barrier();
    }
#undef STAGE

    // epilogue: row = m0 + t*16 + (l>>4)*4 + rr ; col = n0 + w*WN + u*16 + (l&15)
    int crow0 = m0 + ((l >> 4) << 2);
    int ccol0 = n0 + w * WN + (l & 15);
    if (Cpart) {
        float* pp = Cpart + (long)blockIdx.z * partMN;
#pragma unroll
        for (int t = 0; t < 4; ++t)
#pragma unroll
            for (int rr = 0; rr < 4; ++rr) {
                int m = crow0 + t * 16 + rr;
                if (m >= M) continue;
#pragma unroll
                for (int u = 0; u < FC; ++u)
                    pp[(long)m * N + ccol0 + u * 16] = acc[t][u][rr];
            }
    } else {
#pragma unroll
        for (int t = 0; t < 4; ++t)
#pragma unroll
            for (int rr = 0; rr < 4; ++rr) {
                int m = crow0 + t * 16 + rr;
                if (m >= M) continue;
                bf16* crow = Cb + (long)m * ldc;
#pragma unroll
                for (int u = 0; u < FC; ++u) {
                    int n = ccol0 + u * 16;
                    float v = acc[t][u][rr];
                    if (bias) v += bias[n];
                    if (gelu) v = 0.5f * v * (1.f + erff(v * 0.70710678118654752f));
                    crow[n] = __float2bfloat16(v);
                }
            }
    }
}

// ---------------- split-K reduce (FFN2): out[map(m,n)] = sum_z part[z] + bias + res ----------------
__global__ __launch_bounds__(256) void reduce_splitk_k(const float* __restrict__ part, int KS,
                                                       const float* __restrict__ bias,
                                                       const float* __restrict__ res,
                                                       float* __restrict__ out, long roff) {
    int e4 = blockIdx.x * 256 + threadIdx.x;        // 0..262143 (float4 elements)
    int m = e4 >> 8, n4 = e4 & 255;
    float4 s = ((const float4*)part)[e4];
    for (int z = 1; z < KS; ++z) {
        float4 p = ((const float4*)(part + (long)z * 1048576))[e4];
        s.x += p.x; s.y += p.y; s.z += p.z; s.w += p.w;
    }
    float4 bv = ((const float4*)bias)[n4];
    long ro = (long)(m >> 8) * TD + (roff + (m & 255)) * 1024L + n4 * 4;
    float4 rv = *(const float4*)(res + ro);
    s.x += bv.x + rv.x; s.y += bv.y + rv.y; s.z += bv.z + rv.z; s.w += bv.w + rv.w;
    *(float4*)(out + ro) = s;
}

// ---------------- fused Wo-reduce + residual + FFN LayerNorm ----------------
// One row per block. c_pre = part0+part1+bo+x -> out; LN(c_pre) -> t_ln (bf16).
__global__ __launch_bounds__(256) void reduce_ln_k(const float* __restrict__ part,
                                                   const float* __restrict__ bo,
                                                   const float* __restrict__ x,
                                                   float* __restrict__ out, long roff,
                                                   const float* __restrict__ g,
                                                   const float* __restrict__ be,
                                                   bf16* __restrict__ t_ln) {
    int m = blockIdx.x;                  // 0..1023
    int b = m >> 8, r = m & 255;
    int tid = threadIdx.x;
    long ro = (long)b * TD + (roff + r) * 1024L + tid * 4;
    int pi = m * 256 + tid;
    float4 s  = ((const float4*)part)[pi];
    float4 p2 = ((const float4*)(part + 1048576))[pi];
    float4 bv = ((const float4*)bo)[tid];
    float4 rv = *(const float4*)(x + ro);
    float c0 = s.x + p2.x + bv.x + rv.x;
    float c1 = s.y + p2.y + bv.y + rv.y;
    float c2 = s.z + p2.z + bv.z + rv.z;
    float c3 = s.w + p2.w + bv.w + rv.w;
    *(float4*)(out + ro) = make_float4(c0, c1, c2, c3);
    float sum = c0 + c1 + c2 + c3;
    float sq  = c0 * c0 + c1 * c1 + c2 * c2 + c3 * c3;
    for (int off = 32; off > 0; off >>= 1) { sum += __shfl_down(sum, off); sq += __shfl_down(sq, off); }
    __shared__ float red[10];
    int w = tid >> 6;
    if ((tid & 63) == 0) { red[w] = sum; red[4 + w] = sq; }
    __syncthreads();
    if (tid == 0) {
        float ts = red[0] + red[1] + red[2] + red[3];
        float tq = red[4] + red[5] + red[6] + red[7];
        float mean = ts * (1.f / Dm);
        float var = tq * (1.f / Dm) - mean * mean;
        red[8] = mean;
        red[9] = rsqrtf(var + 1e-5f);
    }
    __syncthreads();
    float mean = red[8], rstd = red[9];
    float4 gv = ((const float4*)g)[tid];
    float4 bev = ((const float4*)be)[tid];
    bf16* orow = t_ln + (long)(b * CHUNK + r) * Dm + tid * 4;
    orow[0] = __float2bfloat16((c0 - mean) * rstd * gv.x + bev.x);
    orow[1] = __float2bfloat16((c1 - mean) * rstd * gv.y + bev.y);
    orow[2] = __float2bfloat16((c2 - mean) * rstd * gv.z + bev.z);
    orow[3] = __float2bfloat16((c3 - mean) * rstd * gv.w + bev.w);
}

// ---------------- attention: MFMA flash, 4 waves x 16 queries ----------------
__global__ __launch_bounds__(256) void attn_mfma_k(const bf16* __restrict__ qkv, bf16* __restrict__ o_mat) {
    int qc = blockIdx.x, head = blockIdx.y, b = blockIdx.z;
    int kvh = head >> 2;
    int tid = threadIdx.x, w = tid >> 6, l = tid & 63;
    int m16 = l & 15, h4 = l >> 4;

    __shared__ short Qs[64][64];
    __shared__ short Ks[64][64];
    __shared__ short Vt[64][64];           // [dim][key]
    __shared__ short Ps[4][16][64];        // per-wave P tile [q][key]

    const long rowq0 = (long)b * TC + MG + qc * 64;
    const bf16* kbase = qkv + ((long)b * TC) * 1536 + 1024 + kvh * DH;
    const bf16* vbase = kbase + 256;

#pragma unroll
    for (int p = 0; p < 2; ++p) {
        int rr = p * 32 + (tid >> 3);
        gl16(qkv + (rowq0 + rr) * 1536 + head * DH + (tid & 7) * 8, &Qs[rr][(tid & 7) * 8]);
    }

    float a_m[4] = {-1e30f, -1e30f, -1e30f, -1e30f};
    float a_l[4] = {0.f, 0.f, 0.f, 0.f};
    floatx4 acc_o[4];
#pragma unroll
    for (int dt = 0; dt < 4; ++dt) acc_o[dt] = (floatx4){0.f, 0.f, 0.f, 0.f};
    short8 aq[2];

    int qtok0 = MG + qc * 64 + w * 16 + h4 * 4;
    int ntiles = qc + 2;

    for (int t = 0; t < ntiles; ++t) {
        int jt = t * 64;
#pragma unroll
        for (int p = 0; p < 2; ++p) {
            int rr = p * 32 + (tid >> 3);
            int gk = min(jt + rr, TC - 1);
            gl16(kbase + (long)gk * 1536 + (tid & 7) * 8, &Ks[rr][(tid & 7) * 8]);
        }
#pragma unroll
        for (int p = 0; p < 2; ++p) {
            int cg = p * 4 + w;
            int gk = min(jt + l, TC - 1);
            short8 vv = *(const short8*)(vbase + (long)gk * 1536 + cg * 8);
#pragma unroll
            for (int e = 0; e < 8; ++e) Vt[cg * 8 + e][l] = vv[e];
        }
        __syncthreads();
        if (t == 0) {
            aq[0] = *(const short8*)&Qs[w * 16 + m16][h4 * 8];
            aq[1] = *(const short8*)&Qs[w * 16 + m16][32 + h4 * 8];
        }
        floatx4 s[4];
#pragma unroll
        for (int st = 0; st < 4; ++st) {
            s[st] = (floatx4){0.f, 0.f, 0.f, 0.f};
#pragma unroll
            for (int c = 0; c < 2; ++c) {
                short8 kf = *(const short8*)&Ks[st * 16 + m16][c * 32 + h4 * 8];
                s[st] = __builtin_amdgcn_mfma_f32_16x16x32_bf16(aq[c], kf, s[st], 0, 0, 0);
            }
        }
#pragma unroll
        for (int st = 0; st < 4; ++st) {
            int keyg = jt + st * 16 + m16;
#pragma unroll
            for (int r = 0; r < 4; ++r) {
                float v = s[st][r] * 0.125f;
                s[st][r] = (keyg > qtok0 + r) ? -1e30f : v;
            }
        }
#pragma unroll
        for (int r = 0; r < 4; ++r) {
            float tm = fmaxf(fmaxf(s[0][r], s[1][r]), fmaxf(s[2][r], s[3][r]));
            tm = fmaxf(tm, __shfl_xor(tm, 1));
            tm = fmaxf(tm, __shfl_xor(tm, 2));
            tm = fmaxf(tm, __shfl_xor(tm, 4));
            tm = fmaxf(tm, __shfl_xor(tm, 8));
            float mn = fmaxf(a_m[r], tm);
            float rs = __expf(a_m[r] - mn);
            a_m[r] = mn;
            float ps = 0.f;
#pragma unroll
            for (int st = 0; st < 4; ++st) {
                float p = __expf(s[st][r] - mn);
                s[st][r] = p;
                ps += p;
            }
            ps += __shfl_xor(ps, 1); ps += __shfl_xor(ps, 2);
            ps += __shfl_xor(ps, 4); ps += __shfl_xor(ps, 8);
            a_l[r] = a_l[r] * rs + ps;
#pragma unroll
            for (int dt = 0; dt < 4; ++dt) acc_o[dt][r] *= rs;
#pragma unroll
            for (int st = 0; st < 4; ++st) {
                bf16 hb = __float2bfloat16(s[st][r]);
                Ps[w][h4 * 4 + r][st * 16 + m16] = *reinterpret_cast<short*>(&hb);
            }
        }
#pragma unroll
        for (int c = 0; c < 2; ++c) {
            short8 ap = *(const short8*)&Ps[w][m16][c * 32 + h4 * 8];
#pragma unroll
            for (int dt = 0; dt < 4; ++dt) {
                short8 vf = *(const short8*)&Vt[dt * 16 + m16][c * 32 + h4 * 8];
                acc_o[dt] = __builtin_amdgcn_mfma_f32_16x16x32_bf16(ap, vf, acc_o[dt], 0, 0, 0);
            }
        }
        __syncthreads();
    }

#pragma unroll
    for (int r = 0; r < 4; ++r) {
        float inv = 1.f / a_l[r];
        long row = (long)b * CHUNK + qc * 64 + w * 16 + h4 * 4 + r;
#pragma unroll
        for (int dt = 0; dt < 4; ++dt)
            o_mat[row * Dm + head * DH + dt * 16 + m16] = __float2bfloat16(acc_o[dt][r] * inv);
    }
}

// ---------------- column-sum partials: grid (b=4, rg=8), 256 thr; 32 rows per block ----------------
__global__ __launch_bounds__(256) void col_part_k(const float* __restrict__ c, long stepOff,
                                                  float* __restrict__ colp) {
    int b = blockIdx.x, rg = blockIdx.y;
    int d4 = threadIdx.x;
    const float* base = c + (long)b * TD + stepOff + (long)(rg * 32) * Dm + d4 * 4;
    float4 s = make_float4(0.f, 0.f, 0.f, 0.f);
    for (int r = 0; r < 32; ++r) {
        float4 v = *(const float4*)(base + (long)r * Dm);
        s.x += v.x; s.y += v.y; s.z += v.z; s.w += v.w;
    }
    *(float4*)(colp + ((b * 8 + rg) << 10) + d4 * 4) = s;
}

// ---------------- state update: grid (4, 32) x 256 thr; wave per ss output ----------------
__global__ __launch_bounds__(256) void state_update_k(const float* __restrict__ colp,
                                                      const float* __restrict__ Wsp,
                                                      const float* __restrict__ bsp,
                                                      float* __restrict__ st) {
    int b = blockIdx.x;
    int tid = threadIdx.x, w = tid >> 6, l = tid & 63;
    int ss = blockIdx.y * 4 + w;
    float4 m[4];
#pragma unroll
    for (int t = 0; t < 4; ++t) m[t] = make_float4(0.f, 0.f, 0.f, 0.f);
    for (int rg = 0; rg < 8; ++rg) {
        const float* pr = colp + ((b * 8 + rg) << 10) + l * 16;
#pragma unroll
        for (int t = 0; t < 4; ++t) {
            float4 v = *(const float4*)(pr + t * 4);
            m[t].x += v.x; m[t].y += v.y; m[t].z += v.z; m[t].w += v.w;
        }
    }
    const float* wr = Wsp + (long)ss * Dm + l * 16;
    float a = 0.f;
#pragma unroll
    for (int t = 0; t < 4; ++t) {
        float4 wv = *(const float4*)(wr + t * 4);
        a += m[t].x * wv.x + m[t].y * wv.y + m[t].z * wv.z + m[t].w * wv.w;
    }
    a *= (1.f / CHUNK);
    for (int off = 32; off > 0; off >>= 1) a += __shfl_down(a, off);
    if (l == 0) st[b * SDIM + ss] = a + bsp[ss];
}

// ---------------- orchestration ----------------

extern "C" void kernel_launch(void* const* d_in, const int* in_sizes, int n_in,
                              void* d_out, int out_size, void* d_ws, size_t ws_size,
                              hipStream_t stream) {
    const float* x     = (const float*)d_in[0];
    const float* state = (const float*)d_in[1];
    const float* Wq    = (const float*)d_in[2];
    const float* Wk    = (const float*)d_in[3];
    const float* Wv    = (const float*)d_in[4];
    const float* Wo    = (const float*)d_in[5];
    const float* bo    = (const float*)d_in[6];
    const float* lag   = (const float*)d_in[7];
    const float* lab   = (const float*)d_in[8];
    const float* lfg   = (const float*)d_in[9];
    const float* lfb   = (const float*)d_in[10];
    const float* W1    = (const float*)d_in[11];
    const float* b1    = (const float*)d_in[12];
    const float* W2    = (const float*)d_in[13];
    const float* b2    = (const float*)d_in[14];
    const float* Wsp   = (const float*)d_in[15];
    const float* bsp   = (const float*)d_in[16];
    const float* Wsi   = (const float*)d_in[17];
    const float* bsi   = (const float*)d_in[18];
    const float* gtok  = (const float*)d_in[19];

    float* out = (float*)d_out;
    char*  wsb = (char*)d_ws;

    // workspace layout (bytes); qkvb/u and o_mat/t_ln/colp are time-aliased
    bf16* wqkv  = (bf16*)(wsb);                       // 1536x1024      (3,145,728 B)
    bf16* wo    = (bf16*)(wsb + 3145728);             // 1024x1024      (2,097,152 B)
    bf16* w1    = (bf16*)(wsb + 5242880);             // 4096x1024      (8,388,608 B)
    bf16* w2    = (bf16*)(wsb + 13631488);            // 1024x4096      (8,388,608 B)
    bf16* h_in  = (bf16*)(wsb + 22020096);            // 1152x1024 rows (2,359,296 B)
    char* scrA  = wsb + 24379392;                      // max(qkvb 3.24MB, u 8.39MB)
    bf16* qkvb  = (bf16*)scrA;
    bf16* u     = (bf16*)scrA;
    char* scrB  = wsb + 32768000;                      // o_mat / colp (time-aliased, 2MB)
    bf16* o_mat = (bf16*)scrB;
    bf16* t_ln  = (bf16*)scrB;                         // t_ln written after o_mat consumed
    float* colp = (float*)scrB;
    float* si     = (float*)(wsb + 34865152);          // 4096 f32
    float* st     = (float*)(wsb + 34897920);          // 512 f32
    float* part   = (float*)(wsb + 34901248);          // 2 x 1024x1024 f32 (8,388,608 B)

    // ---- setup: state copy, weight conversion, global-token rows ----
    vcopy_k<<<1, 512, 0, stream>>>(state, st, 512);
    cvt_bf16_k<<<1024, 256, 0, stream>>>(Wq, wqkv,            262144);
    cvt_bf16_k<<< 256, 256, 0, stream>>>(Wk, wqkv + 1048576,   65536);
    cvt_bf16_k<<< 256, 256, 0, stream>>>(Wv, wqkv + 1310720,   65536);
    cvt_bf16_k<<<1024, 256, 0, stream>>>(Wo, wo,              262144);
    cvt_bf16_k<<<4096, 256, 0, stream>>>(W1, w1,             1048576);
    cvt_bf16_k<<<4096, 256, 0, stream>>>(W2, w2,             1048576);
    fill_globals_k<<<128, 256, 0, stream>>>(gtok, h_in);

    for (int s = 0; s < NSTEP; ++s) {
        long roff = (long)s * CHUNK;
        state_proj_k<<<dim3(4, 16), 64, 0, stream>>>(st, Wsi, bsi, si);
        // attn LN -> h_in rows MG..263 (bf16)
        ln_rows_k<<<dim3(256, 4), 256, 0, stream>>>(x, TD, roff, h_in, (long)TC * Dm, MG, lag, lab, si);
        // QKV: [1056 x 1536 x 1024] -> qkvb bf16; grid 24x17 = 408 blocks
        gemm64<64><<<dim3(24, 17, 1), 256, 0, stream>>>(
            h_in, wqkv, Bn * TC, 1536, 1024, 1024,
            qkvb, 1536, nullptr, 0, nullptr, 0L);
        attn_mfma_k<<<dim3(4, 16, 4), 256, 0, stream>>>(qkvb, o_mat);
        // Wo split-K (KS=2): 16x16x2 = 512 blocks -> part; fused reduce(+bo,+x) + FFN LN
        gemm64<64><<<dim3(16, 16, 2), 256, 0, stream>>>(
            o_mat, wo, Bn * CHUNK, 1024, 1024, 512,
            nullptr, 0, nullptr, 0, part, 1048576L);
        reduce_ln_k<<<1024, 256, 0, stream>>>(part, bo, x, out, roff, lfg, lfb, t_ln);
        // FFN1 + gelu -> u bf16; grid 32x16 = 512 blocks (BN=128)
        gemm64<128><<<dim3(32, 16, 1), 256, 0, stream>>>(
            t_ln, w1, Bn * CHUNK, 4096, 1024, 1024,
            u, 4096, b1, 1, nullptr, 0L);
        // FFN2 split-K (KS=2): 16x16x2 = 512 blocks -> part; reduce(+b2,+c_pre) -> out
        gemm64<64><<<dim3(16, 16, 2), 256, 0, stream>>>(
            u, w2, Bn * CHUNK, 1024, 4096, 2048,
            nullptr, 0, nullptr, 0, part, 1048576L);
        reduce_splitk_k<<<1024, 256, 0, stream>>>(part, 2, b2, out, out, roff);
        // state update
        col_part_k<<<dim3(4, 8), 256, 0, stream>>>(out, roff * Dm, colp);
        state_update_k<<<dim3(4, 32), 256, 0, stream>>>(colp, Wsp, bsp, st);
    }
    vcopy_k<<<1, 512, 0, stream>>>(st, out + (long)Bn * Tn * Dm, 512);
}

// Round 7
// 1580.338 us; speedup vs baseline: 7.1212x; 1.0828x over previous
//
#include <hip/hip_runtime.h>
#include <hip/hip_bf16.h>

// Sizes
#define Dm    1024
#define Hn    16
#define KVH   4
#define DH    64
#define CHUNK 256
#define SDIM  128
#define MG    8
#define Bn    4
#define Tn    4096
#define TC    264            // MG + CHUNK
#define NSTEP 16
#define TD    4194304L       // Tn*Dm per batch

typedef __attribute__((ext_vector_type(8))) short short8;
typedef __attribute__((ext_vector_type(4))) float floatx4;
typedef __hip_bfloat16 bf16;

__device__ __forceinline__ void gl16(const void* g, void* l) {
    using GP = const __attribute__((address_space(1))) char*;
    using LP = __attribute__((address_space(3))) char*;
    __builtin_amdgcn_global_load_lds((GP)g, (LP)l, 16, 0, 0);
}
__device__ __forceinline__ float b2f(short s) {
    unsigned int u = ((unsigned int)(unsigned short)s) << 16;
    float f; __builtin_memcpy(&f, &u, 4); return f;
}
__device__ __forceinline__ short f2b(float f) {
    bf16 h = __float2bfloat16(f);
    short s; __builtin_memcpy(&s, &h, 2); return s;
}

// ---------------- utility kernels ----------------

__global__ __launch_bounds__(512) void vcopy_k(const float* __restrict__ s, float* __restrict__ d, int n) {
    int i = blockIdx.x * 512 + threadIdx.x;
    if (i < n) d[i] = s[i];
}

__global__ __launch_bounds__(256) void cvt_bf16_k(const float* __restrict__ s, bf16* __restrict__ d, int n4) {
    int i = blockIdx.x * 256 + threadIdx.x;
    if (i >= n4) return;
    float4 v = ((const float4*)s)[i];
    bf16* o = d + i * 4;
    o[0] = __float2bfloat16(v.x); o[1] = __float2bfloat16(v.y);
    o[2] = __float2bfloat16(v.z); o[3] = __float2bfloat16(v.w);
}

// WsiT[s][d] = bf16(Wsi[d][s])  (Wsi is [1024][128])
__global__ __launch_bounds__(256) void wsiT_k(const float* __restrict__ Wsi, bf16* __restrict__ WsiT) {
    int idx = blockIdx.x * 256 + threadIdx.x;     // 0..131071
    int s = idx >> 10, d = idx & 1023;
    WsiT[idx] = __float2bfloat16(Wsi[d * SDIM + s]);
}

// bfused[n] = wqkv[n] . bsi   (1536 outputs, K=1024)
__global__ __launch_bounds__(64) void bfused_k(const bf16* __restrict__ wqkv, const float* __restrict__ bsi,
                                               float* __restrict__ bfused) {
    int n = blockIdx.x * 64 + threadIdx.x;
    const bf16* wr = wqkv + (long)n * 1024;
    float a = 0.f;
    for (int k8 = 0; k8 < 128; ++k8) {
        short8 wv = *(const short8*)(wr + k8 * 8);
#pragma unroll
        for (int e = 0; e < 8; ++e) a += b2f(wv[e]) * bsi[k8 * 8 + e];
    }
    bfused[n] = a;
}

// sib[b][n] = st[b] . Wfused[n] + bfused[n]   (grid (4,24) x 64)
__global__ __launch_bounds__(64) void sib_k(const float* __restrict__ st, const bf16* __restrict__ Wf,
                                            const float* __restrict__ bfused, float* __restrict__ sib) {
    int b = blockIdx.x, n = blockIdx.y * 64 + threadIdx.x;
    const float* sr = st + b * SDIM;
    const bf16* wr = Wf + (long)n * SDIM;
    float a = bfused[n];
#pragma unroll
    for (int k8 = 0; k8 < 16; ++k8) {
        short8 wv = *(const short8*)(wr + k8 * 8);
#pragma unroll
        for (int e = 0; e < 8; ++e) a += sr[k8 * 8 + e] * b2f(wv[e]);
    }
    sib[b * 1536 + n] = a;
}

// qkv_s[b][8+r][n] += sib[b][n]  (grid (4,256) x 192, 8 bf16/thread)
__global__ __launch_bounds__(192) void addsi_k(bf16* __restrict__ qkv_s, const float* __restrict__ sib) {
    int b = blockIdx.x, r = MG + blockIdx.y, n0 = threadIdx.x * 8;
    bf16* p = qkv_s + ((long)(b * TC + r) * 1536 + n0);
    const float* sb = sib + b * 1536 + n0;
    short8 v = *(const short8*)p;
    short8 o;
#pragma unroll
    for (int e = 0; e < 8; ++e) o[e] = f2b(b2f(v[e]) + sb[e]);
    *(short8*)p = o;
}

// group LN: grid (1056, 4) x 256. bx -> (s_local, r). r<8: gtok raw; else LN(x row).
__global__ __launch_bounds__(256) void lng_k(const float* __restrict__ x, const float* __restrict__ gtok,
                                             const float* __restrict__ g, const float* __restrict__ be,
                                             bf16* __restrict__ lnxg, int gstep) {
    int bx = blockIdx.x, b = blockIdx.y, tid = threadIdx.x;
    int sl = bx / 264, r = bx - sl * 264;
    bf16* orow = lnxg + (long)((sl * 4 + b) * 264 + r) * 1024 + tid * 4;
    if (r < MG) {
        float4 v = *(const float4*)(gtok + r * 1024 + tid * 4);
        orow[0] = __float2bfloat16(v.x); orow[1] = __float2bfloat16(v.y);
        orow[2] = __float2bfloat16(v.z); orow[3] = __float2bfloat16(v.w);
        return;
    }
    const float* row = x + (long)b * TD + ((long)(gstep * 4 + sl) * 256 + (r - MG)) * 1024;
    float4 v = *(const float4*)(row + tid * 4);
    float s = v.x + v.y + v.z + v.w;
    float q = v.x * v.x + v.y * v.y + v.z * v.z + v.w * v.w;
    for (int off = 32; off > 0; off >>= 1) { s += __shfl_down(s, off); q += __shfl_down(q, off); }
    __shared__ float red[10];
    int w = tid >> 6;
    if ((tid & 63) == 0) { red[w] = s; red[4 + w] = q; }
    __syncthreads();
    if (tid == 0) {
        float ts = red[0] + red[1] + red[2] + red[3];
        float tq = red[4] + red[5] + red[6] + red[7];
        float mean = ts * (1.f / Dm);
        float var = tq * (1.f / Dm) - mean * mean;
        red[8] = mean;
        red[9] = rsqrtf(var + 1e-5f);
    }
    __syncthreads();
    float mean = red[8], rstd = red[9];
    int d = tid * 4;
    float4 gv = *(const float4*)(g + d);
    float4 bv = *(const float4*)(be + d);
    orow[0] = __float2bfloat16((v.x - mean) * rstd * gv.x + bv.x);
    orow[1] = __float2bfloat16((v.y - mean) * rstd * gv.y + bv.y);
    orow[2] = __float2bfloat16((v.z - mean) * rstd * gv.z + bv.z);
    orow[3] = __float2bfloat16((v.w - mean) * rstd * gv.w + bv.w);
}

// ---------------- bf16 MFMA GEMM, 64xBN tile, BK=64 phases, 2-buffer, optional split-K ----------------
template<int BN>
__global__ __launch_bounds__(256) void gemm64(
    const bf16* __restrict__ A, const bf16* __restrict__ W,
    int M, int N, int K, int kspan,
    bf16* __restrict__ Cb, int ldc, const float* __restrict__ bias, int gelu,
    float* __restrict__ Cpart, long partMN)
{
    constexpr int NSEG = 4 + BN / 16;     // 1KB segments per 32-k half
    constexpr int SEGW = NSEG / 4;        // segments per wave per half
    constexpr int FC   = BN / 64;
    constexpr int WN   = BN / 4;
    constexpr int HALFB = NSEG * 1024;    // bytes per 32-k half
    constexpr int PHB   = 2 * HALFB;      // bytes per 64-k phase buffer
    __shared__ short S[PHB];              // = 2*PHB bytes = two phase buffers

    int tid = threadIdx.x;
    int w = tid >> 6, l = tid & 63;
    int m0 = blockIdx.y << 6, n0 = blockIdx.x * BN;
    long kb = (long)blockIdx.z * kspan;

    const bf16* gp[SEGW];
    int so[SEGW];
#pragma unroll
    for (int si = 0; si < SEGW; ++si) {
        int s = w + si * 4;
        const bf16* base = (s < 4) ? (A + (long)(m0 + s * 16 + (l >> 2)) * K)
                                   : (W + (long)(n0 + (s - 4) * 16 + (l >> 2)) * K);
        gp[si] = base + ((l & 3) << 3) + kb;
        so[si] = s * 1024 + l * 16;
    }
    char* cS = (char*)S;

    floatx4 acc[4][FC];
#pragma unroll
    for (int t = 0; t < 4; ++t)
#pragma unroll
        for (int u = 0; u < FC; ++u) acc[t][u] = (floatx4){0.f, 0.f, 0.f, 0.f};

    int arow = l & 15;
    int acol = (l >> 4) << 3;
    int np = kspan >> 6;

#define STAGE(p)                                                         \
    {                                                                    \
        int kt_ = (p) << 6;                                              \
        char* b_ = cS + ((p) & 1) * PHB;                                 \
        _Pragma("unroll")                                                \
        for (int si = 0; si < SEGW; ++si) {                              \
            gl16(gp[si] + kt_, b_ + so[si]);                             \
            gl16(gp[si] + kt_ + 32, b_ + HALFB + so[si]);                \
        }                                                                \
    }

    STAGE(0)
    for (int p = 0; p < np; ++p) {
        if (p + 1 < np) {
            STAGE(p + 1)
            if constexpr (SEGW == 2) asm volatile("s_waitcnt vmcnt(4)" ::: "memory");
            else                     asm volatile("s_waitcnt vmcnt(6)" ::: "memory");
        } else {
            asm volatile("s_waitcnt vmcnt(0)" ::: "memory");
        }
        __builtin_amdgcn_s_barrier();
        __builtin_amdgcn_sched_barrier(0);
        const short* buf = S + (p & 1) * (PHB / 2);
#pragma unroll
        for (int kh = 0; kh < 2; ++kh) {
            const short* hb = buf + kh * (HALFB / 2);
            short8 a[4], b[FC];
#pragma unroll
            for (int t = 0; t < 4; ++t)
                a[t] = *(const short8*)&hb[(t * 16 + arow) * 32 + acol];
#pragma unroll
            for (int u = 0; u < FC; ++u)
                b[u] = *(const short8*)&hb[2048 + (w * WN + u * 16 + arow) * 32 + acol];
#pragma unroll
            for (int t = 0; t < 4; ++t)
#pragma unroll
                for (int u = 0; u < FC; ++u)
                    acc[t][u] = __builtin_amdgcn_mfma_f32_16x16x32_bf16(a[t], b[u], acc[t][u], 0, 0, 0);
        }
        __builtin_amdgcn_sched_barrier(0);
        __builtin_amdgcn_s_barrier();
    }
#undef STAGE

    int crow0 = m0 + ((l >> 4) << 2);
    int ccol0 = n0 + w * WN + (l & 15);
    if (Cpart) {
        float* pp = Cpart + (long)blockIdx.z * partMN;
#pragma unroll
        for (int t = 0; t < 4; ++t)
#pragma unroll
            for (int rr = 0; rr < 4; ++rr) {
                int m = crow0 + t * 16 + rr;
                if (m >= M) continue;
#pragma unroll
                for (int u = 0; u < FC; ++u)
                    pp[(long)m * N + ccol0 + u * 16] = acc[t][u][rr];
            }
    } else {
#pragma unroll
        for (int t = 0; t < 4; ++t)
#pragma unroll
            for (int rr = 0; rr < 4; ++rr) {
                int m = crow0 + t * 16 + rr;
                if (m >= M) continue;
                bf16* crow = Cb + (long)m * ldc;
#pragma unroll
                for (int u = 0; u < FC; ++u) {
                    int n = ccol0 + u * 16;
                    float v = acc[t][u][rr];
                    if (bias) v += bias[n];
                    if (gelu) v = 0.5f * v * (1.f + erff(v * 0.70710678118654752f));
                    crow[n] = __float2bfloat16(v);
                }
            }
    }
}

// ---------------- fused Wo-reduce + residual + FFN LayerNorm ----------------
__global__ __launch_bounds__(256) void reduce_ln_k(const float* __restrict__ part,
                                                   const float* __restrict__ bo,
                                                   const float* __restrict__ x,
                                                   float* __restrict__ out, long roff,
                                                   const float* __restrict__ g,
                                                   const float* __restrict__ be,
                                                   bf16* __restrict__ t_ln) {
    int m = blockIdx.x;                  // 0..1023
    int b = m >> 8, r = m & 255;
    int tid = threadIdx.x;
    long ro = (long)b * TD + (roff + r) * 1024L + tid * 4;
    int pi = m * 256 + tid;
    float4 s  = ((const float4*)part)[pi];
    float4 p2 = ((const float4*)(part + 1048576))[pi];
    float4 bv = ((const float4*)bo)[tid];
    float4 rv = *(const float4*)(x + ro);
    float c0 = s.x + p2.x + bv.x + rv.x;
    float c1 = s.y + p2.y + bv.y + rv.y;
    float c2 = s.z + p2.z + bv.z + rv.z;
    float c3 = s.w + p2.w + bv.w + rv.w;
    *(float4*)(out + ro) = make_float4(c0, c1, c2, c3);
    float sum = c0 + c1 + c2 + c3;
    float sq  = c0 * c0 + c1 * c1 + c2 * c2 + c3 * c3;
    for (int off = 32; off > 0; off >>= 1) { sum += __shfl_down(sum, off); sq += __shfl_down(sq, off); }
    __shared__ float red[10];
    int w = tid >> 6;
    if ((tid & 63) == 0) { red[w] = sum; red[4 + w] = sq; }
    __syncthreads();
    if (tid == 0) {
        float ts = red[0] + red[1] + red[2] + red[3];
        float tq = red[4] + red[5] + red[6] + red[7];
        float mean = ts * (1.f / Dm);
        float var = tq * (1.f / Dm) - mean * mean;
        red[8] = mean;
        red[9] = rsqrtf(var + 1e-5f);
    }
    __syncthreads();
    float mean = red[8], rstd = red[9];
    float4 gv = ((const float4*)g)[tid];
    float4 bev = ((const float4*)be)[tid];
    bf16* orow = t_ln + (long)(b * CHUNK + r) * Dm + tid * 4;
    orow[0] = __float2bfloat16((c0 - mean) * rstd * gv.x + bev.x);
    orow[1] = __float2bfloat16((c1 - mean) * rstd * gv.y + bev.y);
    orow[2] = __float2bfloat16((c2 - mean) * rstd * gv.z + bev.z);
    orow[3] = __float2bfloat16((c3 - mean) * rstd * gv.w + bev.w);
}

// ---------------- fused FFN2-reduce + residual + column partials ----------------
// grid (b=4, rg=32) x 256; 8 rows each. out = part0+part1+b2+c_pre; colp[b][rg][d] = colsum.
__global__ __launch_bounds__(256) void reduce_colpart_k(const float* __restrict__ part,
                                                        const float* __restrict__ bias,
                                                        float* __restrict__ out, long roff,
                                                        float* __restrict__ colp) {
    int b = blockIdx.x, rg = blockIdx.y, tid = threadIdx.x;
    float4 bv = ((const float4*)bias)[tid];
    float4 cs = make_float4(0.f, 0.f, 0.f, 0.f);
#pragma unroll
    for (int r8 = 0; r8 < 8; ++r8) {
        int r = rg * 8 + r8;
        int pi = (b * 256 + r) * 256 + tid;
        float4 s  = ((const float4*)part)[pi];
        float4 p2 = ((const float4*)(part + 1048576))[pi];
        long ro = (long)b * TD + (roff + r) * 1024L + tid * 4;
        float4 rv = *(const float4*)(out + ro);
        float4 v = make_float4(s.x + p2.x + bv.x + rv.x, s.y + p2.y + bv.y + rv.y,
                               s.z + p2.z + bv.z + rv.z, s.w + p2.w + bv.w + rv.w);
        *(float4*)(out + ro) = v;
        cs.x += v.x; cs.y += v.y; cs.z += v.z; cs.w += v.w;
    }
    *(float4*)(colp + ((b * 32 + rg) << 10) + tid * 4) = cs;
}

// ---------------- attention: MFMA flash, 4 waves x 16 queries ----------------
__global__ __launch_bounds__(256) void attn_mfma_k(const bf16* __restrict__ qkv, bf16* __restrict__ o_mat) {
    int qc = blockIdx.x, head = blockIdx.y, b = blockIdx.z;
    int kvh = head >> 2;
    int tid = threadIdx.x, w = tid >> 6, l = tid & 63;
    int m16 = l & 15, h4 = l >> 4;

    __shared__ short Qs[64][64];
    __shared__ short Ks[64][64];
    __shared__ short Vt[64][64];           // [dim][key]
    __shared__ short Ps[4][16][64];        // per-wave P tile [q][key]

    const long rowq0 = (long)b * TC + MG + qc * 64;
    const bf16* kbase = qkv + ((long)b * TC) * 1536 + 1024 + kvh * DH;
    const bf16* vbase = kbase + 256;

#pragma unroll
    for (int p = 0; p < 2; ++p) {
        int rr = p * 32 + (tid >> 3);
        gl16(qkv + (rowq0 + rr) * 1536 + head * DH + (tid & 7) * 8, &Qs[rr][(tid & 7) * 8]);
    }

    float a_m[4] = {-1e30f, -1e30f, -1e30f, -1e30f};
    float a_l[4] = {0.f, 0.f, 0.f, 0.f};
    floatx4 acc_o[4];
#pragma unroll
    for (int dt = 0; dt < 4; ++dt) acc_o[dt] = (floatx4){0.f, 0.f, 0.f, 0.f};
    short8 aq[2];

    int qtok0 = MG + qc * 64 + w * 16 + h4 * 4;
    int ntiles = qc + 2;

    for (int t = 0; t < ntiles; ++t) {
        int jt = t * 64;
#pragma unroll
        for (int p = 0; p < 2; ++p) {
            int rr = p * 32 + (tid >> 3);
            int gk = min(jt + rr, TC - 1);
            gl16(kbase + (long)gk * 1536 + (tid & 7) * 8, &Ks[rr][(tid & 7) * 8]);
        }
#pragma unroll
        for (int p = 0; p < 2; ++p) {
            int cg = p * 4 + w;
            int gk = min(jt + l, TC - 1);
            short8 vv = *(const short8*)(vbase + (long)gk * 1536 + cg * 8);
#pragma unroll
            for (int e = 0; e < 8; ++e) Vt[cg * 8 + e][l] = vv[e];
        }
        __syncthreads();
        if (t == 0) {
            aq[0] = *(const short8*)&Qs[w * 16 + m16][h4 * 8];
            aq[1] = *(const short8*)&Qs[w * 16 + m16][32 + h4 * 8];
        }
        floatx4 s[4];
#pragma unroll
        for (int st = 0; st < 4; ++st) {
            s[st] = (floatx4){0.f, 0.f, 0.f, 0.f};
#pragma unroll
            for (int c = 0; c < 2; ++c) {
                short8 kf = *(const short8*)&Ks[st * 16 + m16][c * 32 + h4 * 8];
                s[st] = __builtin_amdgcn_mfma_f32_16x16x32_bf16(aq[c], kf, s[st], 0, 0, 0);
            }
        }
#pragma unroll
        for (int st = 0; st < 4; ++st) {
            int keyg = jt + st * 16 + m16;
#pragma unroll
            for (int r = 0; r < 4; ++r) {
                float v = s[st][r] * 0.125f;
                s[st][r] = (keyg > qtok0 + r) ? -1e30f : v;
            }
        }
#pragma unroll
        for (int r = 0; r < 4; ++r) {
            float tm = fmaxf(fmaxf(s[0][r], s[1][r]), fmaxf(s[2][r], s[3][r]));
            tm = fmaxf(tm, __shfl_xor(tm, 1));
            tm = fmaxf(tm, __shfl_xor(tm, 2));
            tm = fmaxf(tm, __shfl_xor(tm, 4));
            tm = fmaxf(tm, __shfl_xor(tm, 8));
            float mn = fmaxf(a_m[r], tm);
            float rs = __expf(a_m[r] - mn);
            a_m[r] = mn;
            float ps = 0.f;
#pragma unroll
            for (int st = 0; st < 4; ++st) {
                float p = __expf(s[st][r] - mn);
                s[st][r] = p;
                ps += p;
            }
            ps += __shfl_xor(ps, 1); ps += __shfl_xor(ps, 2);
            ps += __shfl_xor(ps, 4); ps += __shfl_xor(ps, 8);
            a_l[r] = a_l[r] * rs + ps;
#pragma unroll
            for (int dt = 0; dt < 4; ++dt) acc_o[dt][r] *= rs;
#pragma unroll
            for (int st = 0; st < 4; ++st) {
                Ps[w][h4 * 4 + r][st * 16 + m16] = f2b(s[st][r]);
            }
        }
#pragma unroll
        for (int c = 0; c < 2; ++c) {
            short8 ap = *(const short8*)&Ps[w][m16][c * 32 + h4 * 8];
#pragma unroll
            for (int dt = 0; dt < 4; ++dt) {
                short8 vf = *(const short8*)&Vt[dt * 16 + m16][c * 32 + h4 * 8];
                acc_o[dt] = __builtin_amdgcn_mfma_f32_16x16x32_bf16(ap, vf, acc_o[dt], 0, 0, 0);
            }
        }
        __syncthreads();
    }

#pragma unroll
    for (int r = 0; r < 4; ++r) {
        float inv = 1.f / a_l[r];
        long row = (long)b * CHUNK + qc * 64 + w * 16 + h4 * 4 + r;
#pragma unroll
        for (int dt = 0; dt < 4; ++dt)
            o_mat[row * Dm + head * DH + dt * 16 + m16] = __float2bfloat16(acc_o[dt][r] * inv);
    }
}

// ---------------- state update: grid (4, 32) x 256 thr; wave per ss output ----------------
__global__ __launch_bounds__(256) void state_update_k(const float* __restrict__ colp,
                                                      const float* __restrict__ Wsp,
                                                      const float* __restrict__ bsp,
                                                      float* __restrict__ st) {
    int b = blockIdx.x;
    int tid = threadIdx.x, w = tid >> 6, l = tid & 63;
    int ss = blockIdx.y * 4 + w;
    float4 m[4];
#pragma unroll
    for (int t = 0; t < 4; ++t) m[t] = make_float4(0.f, 0.f, 0.f, 0.f);
    for (int rg = 0; rg < 32; ++rg) {
        const float* pr = colp + ((b * 32 + rg) << 10) + l * 16;
#pragma unroll
        for (int t = 0; t < 4; ++t) {
            float4 v = *(const float4*)(pr + t * 4);
            m[t].x += v.x; m[t].y += v.y; m[t].z += v.z; m[t].w += v.w;
        }
    }
    const float* wr = Wsp + (long)ss * Dm + l * 16;
    float a = 0.f;
#pragma unroll
    for (int t = 0; t < 4; ++t) {
        float4 wv = *(const float4*)(wr + t * 4);
        a += m[t].x * wv.x + m[t].y * wv.y + m[t].z * wv.z + m[t].w * wv.w;
    }
    a *= (1.f / CHUNK);
    for (int off = 32; off > 0; off >>= 1) a += __shfl_down(a, off);
    if (l == 0) st[b * SDIM + ss] = a + bsp[ss];
}

// ---------------- orchestration ----------------

extern "C" void kernel_launch(void* const* d_in, const int* in_sizes, int n_in,
                              void* d_out, int out_size, void* d_ws, size_t ws_size,
                              hipStream_t stream) {
    const float* x     = (const float*)d_in[0];
    const float* state = (const float*)d_in[1];
    const float* Wq    = (const float*)d_in[2];
    const float* Wk    = (const float*)d_in[3];
    const float* Wv    = (const float*)d_in[4];
    const float* Wo    = (const float*)d_in[5];
    const float* bo    = (const float*)d_in[6];
    const float* lag   = (const float*)d_in[7];
    const float* lab   = (const float*)d_in[8];
    const float* lfg   = (const float*)d_in[9];
    const float* lfb   = (const float*)d_in[10];
    const float* W1    = (const float*)d_in[11];
    const float* b1    = (const float*)d_in[12];
    const float* W2    = (const float*)d_in[13];
    const float* b2    = (const float*)d_in[14];
    const float* Wsp   = (const float*)d_in[15];
    const float* bsp   = (const float*)d_in[16];
    const float* Wsi   = (const float*)d_in[17];
    const float* bsi   = (const float*)d_in[18];
    const float* gtok  = (const float*)d_in[19];

    float* out = (float*)d_out;
    char*  wsb = (char*)d_ws;

    // workspace layout (bytes)
    bf16* wqkv   = (bf16*)(wsb);                      // 1536x1024   3,145,728
    bf16* wo     = (bf16*)(wsb + 3145728);            // 1024x1024   2,097,152
    bf16* w1     = (bf16*)(wsb + 5242880);            // 4096x1024   8,388,608
    bf16* w2     = (bf16*)(wsb + 13631488);           // 1024x4096   8,388,608
    bf16* Wfused = (bf16*)(wsb + 22020096);           // 1536x128      393,216
    bf16* WsiT   = (bf16*)(wsb + 22413312);           // 128x1024      262,144
    float* bfused= (float*)(wsb + 22675456);          // 1536            6,144
    float* sib   = (float*)(wsb + 22681600);          // 4x1536         24,576
    float* st    = (float*)(wsb + 22706176);          // 512             2,048
    bf16* qkvg   = (bf16*)(wsb + 22708224);           // 4x4x264x1536  12,976,128
    char* R1     = wsb + 35684352;                    // lnxg (8,650,752) ∪ u (8,388,608)
    bf16* lnxg   = (bf16*)R1;
    bf16* u      = (bf16*)R1;
    float* part  = (float*)(wsb + 44335104);          // 2x1024x1024 f32  8,388,608
    char* scrB   = wsb + 52723712;                    // o_mat ∪ t_ln ∪ colp (2,097,152)
    bf16* o_mat  = (bf16*)scrB;
    bf16* t_ln   = (bf16*)scrB;
    float* colp  = (float*)scrB;                      // 4x32x1024 f32 = 512KB
    // total ≈ 54.8 MB

    // ---- setup ----
    vcopy_k<<<1, 512, 0, stream>>>(state, st, 512);
    cvt_bf16_k<<<1024, 256, 0, stream>>>(Wq, wqkv,            262144);
    cvt_bf16_k<<< 256, 256, 0, stream>>>(Wk, wqkv + 1048576,   65536);
    cvt_bf16_k<<< 256, 256, 0, stream>>>(Wv, wqkv + 1310720,   65536);
    cvt_bf16_k<<<1024, 256, 0, stream>>>(Wo, wo,              262144);
    cvt_bf16_k<<<4096, 256, 0, stream>>>(W1, w1,             1048576);
    cvt_bf16_k<<<4096, 256, 0, stream>>>(W2, w2,             1048576);
    wsiT_k<<<512, 256, 0, stream>>>(Wsi, WsiT);
    // Wfused = wqkv @ WsiT^T : M=1536, N=128, K=1024
    gemm64<64><<<dim3(2, 24, 1), 256, 0, stream>>>(
        wqkv, WsiT, 1536, 128, 1024, 1024,
        Wfused, 128, nullptr, 0, nullptr, 0L);
    bfused_k<<<24, 64, 0, stream>>>(wqkv, bsi, bfused);

    for (int s = 0; s < NSTEP; ++s) {
        long roff = (long)s * CHUNK;
        if ((s & 3) == 0) {
            int g = s >> 2;
            // build group LN input (incl. gtok rows), then group QKV GEMM: M=4224
            lng_k<<<dim3(1056, 4), 256, 0, stream>>>(x, gtok, lag, lab, lnxg, g);
            gemm64<64><<<dim3(24, 66, 1), 256, 0, stream>>>(
                lnxg, wqkv, 4224, 1536, 1024, 1024,
                qkvg, 1536, nullptr, 0, nullptr, 0L);
        }
        bf16* qkv_s = qkvg + (long)(s & 3) * (4 * 264 * 1536);
        // rank-128 state correction: sib = st@Wfused^T + bfused; qkv chunk rows += sib
        sib_k<<<dim3(4, 24), 64, 0, stream>>>(st, Wfused, bfused, sib);
        addsi_k<<<dim3(4, 256), 192, 0, stream>>>(qkv_s, sib);
        attn_mfma_k<<<dim3(4, 16, 4), 256, 0, stream>>>(qkv_s, o_mat);
        // Wo split-K (KS=2) -> part; fused reduce(+bo,+x) + FFN LN
        gemm64<64><<<dim3(16, 16, 2), 256, 0, stream>>>(
            o_mat, wo, Bn * CHUNK, 1024, 1024, 512,
            nullptr, 0, nullptr, 0, part, 1048576L);
        reduce_ln_k<<<1024, 256, 0, stream>>>(part, bo, x, out, roff, lfg, lfb, t_ln);
        // FFN1 + gelu -> u bf16
        gemm64<128><<<dim3(32, 16, 1), 256, 0, stream>>>(
            t_ln, w1, Bn * CHUNK, 4096, 1024, 1024,
            u, 4096, b1, 1, nullptr, 0L);
        // FFN2 split-K (KS=2) -> part; fused reduce(+b2,+c_pre) + column partials
        gemm64<64><<<dim3(16, 16, 2), 256, 0, stream>>>(
            u, w2, Bn * CHUNK, 1024, 4096, 2048,
            nullptr, 0, nullptr, 0, part, 1048576L);
        reduce_colpart_k<<<dim3(4, 32), 256, 0, stream>>>(part, b2, out, roff, colp);
        state_update_k<<<dim3(4, 32), 256, 0, stream>>>(colp, Wsp, bsp, st);
    }
    vcopy_k<<<1, 512, 0, stream>>>(st, out + (long)Bn * Tn * Dm, 512);
}